// Round 8
// baseline (150.824 us; speedup 1.0000x reference)
//
#include <hip/hip_runtime.h>
#include <cstdint>
#include <cstddef>

#define HH 1024
#define WW 1024
#define NB 4

typedef _Float16 half8 __attribute__((ext_vector_type(8)));
typedef _Float16 half4 __attribute__((ext_vector_type(4)));
typedef float f32x4 __attribute__((ext_vector_type(4)));
typedef unsigned long long ull;

// ---------------------------------------------------------------------------
// Fast clear for the 32 MB packed-cell buffer (~5.5 TB/s).
// ---------------------------------------------------------------------------
__global__ __launch_bounds__(256)
void clear_cells(float4* __restrict__ p, int n4) {
  int stride = gridDim.x * blockDim.x;
  float4 z; z.x = 0.f; z.y = 0.f; z.z = 0.f; z.w = 0.f;
  for (int i = blockIdx.x * blockDim.x + threadIdx.x; i < n4; i += stride)
    p[i] = z;
}

// ---------------------------------------------------------------------------
// Scatter: 4 per-cell stats packed in ONE u64 updated by CAS.
//   [63:48] zmax_q16 | [47:32] 65535-zmin_q16 | [31:16] iv_q16 | [15:0] cnt
// All-zero word == empty cell. Optimistic first CAS (~90% one-shot).
// ---------------------------------------------------------------------------
__device__ __forceinline__ ull merge_cell(ull a, unsigned zq, unsigned zn, unsigned iq) {
  unsigned cnt = (unsigned)(a & 0xFFFFull);
  unsigned civ = (unsigned)((a >> 16) & 0xFFFFull);
  unsigned czn = (unsigned)((a >> 32) & 0xFFFFull);
  unsigned czx = (unsigned)(a >> 48);
  cnt = (cnt < 65535u) ? cnt + 1u : cnt;
  civ = civ > iq ? civ : iq;
  czn = czn > zn ? czn : zn;
  czx = czx > zq ? czx : zq;
  return (ull)cnt | ((ull)civ << 16) | ((ull)czn << 32) | ((ull)czx << 48);
}

__global__ __launch_bounds__(256)
void scatter_points_packed(const float* __restrict__ pts, int n,
                           ull* __restrict__ cell) {
  const float xs   = (float)(1024.0 / 69.12);
  const float ys   = (float)(1024.0 / (39.68 + 39.68));
  const float yoff = 39.68f;
  int i = blockIdx.x * blockDim.x + threadIdx.x;
  if (i >= n) return;
  float b  = pts[(size_t)i * 5 + 0];
  float x  = pts[(size_t)i * 5 + 1];
  float y  = pts[(size_t)i * 5 + 2];
  float z  = pts[(size_t)i * 5 + 3];
  float it = pts[(size_t)i * 5 + 4];
  int xp = (int)(x * xs);                 // trunc toward zero == astype(int32)
  int yp = (int)((y + yoff) * ys);
  if (xp < 0 || xp >= WW || yp < 0 || yp >= HH) return;
  int lin = ((int)b * HH + yp) * WW + xp;

  float zc = fminf(fmaxf(z, -3.f), 1.f);
  unsigned zq = (unsigned)(int)((zc + 3.f) * (65535.f / 4.f) + 0.5f);
  if (zq > 65535u) zq = 65535u;
  float ic = fminf(fmaxf(it, 0.f), 1.f);
  unsigned iq = (unsigned)(int)(ic * 65535.f + 0.5f);
  if (iq > 65535u) iq = 65535u;
  unsigned zn = 65535u - zq;

  ull g = atomicCAS(&cell[lin], 0ull, merge_cell(0ull, zq, zn, iq));
  while (g != 0ull) {
    ull r = atomicCAS(&cell[lin], g, merge_cell(g, zq, zn, iq));
    if (r == g) break;
    g = r;
  }
}

// ---------------------------------------------------------------------------
// Implicit-GEMM conv3x3 + bias + BN + ReLU (+2x2 maxpool) via MFMA f16.
// Per block: 16 y-rows x PXT x-cols, co group [cobase, cobase+COp).
// INMODE 0: packed-u64 BEV input, CIp=4 tap-PAIR K-packing (K=64, KS=2):
//   k-slot = p*8+j, p=pair 0..7, j<4 -> tap tA(p) ci=j, j>=4 -> tap tA(p)+1
//   (even p<6) or zero-weight pad. A half8 load spans cells (col,col+1).
// INMODE 1: channels-last f16 [b][y][x][CI], k = tap*CIp+ci.
// OUTCL: true = channels-last f16 out; false = NCHW f32 (final layer).
// ---------------------------------------------------------------------------
template<int CI, int CIp, int COT, int COp, int HWI, int PXT, int KS,
         bool POOL, int INMODE, bool OUTCL>
__global__ __launch_bounds__(256)
void conv_mfma(const void* __restrict__ in, void* __restrict__ outv,
               const float* __restrict__ wgt, const float* __restrict__ bias,
               const float* __restrict__ gam, const float* __restrict__ bet,
               const float* __restrict__ mean, const float* __restrict__ var) {
  constexpr int PYT  = 16;
  constexpr int NT   = COp / 16;
  constexpr int XH   = PXT / 16;
  constexpr int NCOL = PXT + 2;
  constexpr int NCELL = (PYT + 2) * NCOL;
  constexpr int WROW = KS * 32 + 8;
  constexpr int INE  = NCELL * CIp;
  constexpr int L2C  = (CIp == 8) ? 3 : ((CIp == 16) ? 4 : ((CIp == 32) ? 5 : 2));
  constexpr int KTOT = 9 * CIp;
  constexpr int COR  = (COT < COp) ? COT : COp;
  constexpr int PXH  = PXT / 2;
  static_assert((CIp % 8 == 0) || (INMODE == 0 && CIp == 4), "");
  static_assert(INMODE != 0 || (CI == 4 && CIp == 4 && KS == 2), "");
  static_assert(COp % 16 == 0, "");
  static_assert(!OUTCL || (POOL && COT % 8 == 0), "");
  static_assert(!POOL || 8 * PXH * COp * 2 <= INE * 2, "out overlay fits");
  static_assert(POOL || COp * 66 * 4 <= INE * 2, "out overlay fits");

  __shared__ __align__(16) char s_raw[INE * 2 + COp * WROW * 2 + COp * 8];
  _Float16* s_in = (_Float16*)s_raw;
  _Float16* s_w  = (_Float16*)(s_raw + INE * 2);
  float* s_scale = (float*)(s_raw + INE * 2 + (size_t)COp * WROW * 2);
  float* s_shift = s_scale + COp;

  const int cobase = blockIdx.y * COp;
  const int b = blockIdx.z;
  constexpr int NPX = HWI / PXT;
  const int pyi = blockIdx.x / NPX;
  const int pxi = blockIdx.x - pyi * NPX;
  const int y0 = pyi * PYT, x0 = pxi * PXT;

  half8 zv;
  #pragma unroll
  for (int q = 0; q < 8; ++q) zv[q] = (_Float16)0.f;

  // ---- stage input patch (one cell per iteration; all ci vectorized)
  if constexpr (INMODE == 0) {
    const ull* pin = (const ull*)in;
    for (int t = threadIdx.x; t < NCELL; t += 256) {
      int col = t % NCOL;
      int row = t / NCOL;
      int gy = y0 - 1 + row, gx = x0 - 1 + col;
      half4 v;
      v[0] = (_Float16)0.f; v[1] = (_Float16)0.f;
      v[2] = (_Float16)0.f; v[3] = (_Float16)0.f;
      if (gy >= 0 && gy < HH && gx >= 0 && gx < WW) {
        ull pv = pin[((size_t)b * HH + gy) * WW + gx];
        unsigned cnt = (unsigned)(pv & 0xFFFFull);
        unsigned ivq = (unsigned)((pv >> 16) & 0xFFFFull);
        unsigned znq = (unsigned)((pv >> 32) & 0xFFFFull);
        unsigned zxq = (unsigned)(pv >> 48);
        float c0, c1, c2, c3;
        if (cnt == 0) { c0 = 0.02f; c1 = 10.f; c2 = -10.f; c3 = 0.f; }
        else {
          c0 = (float)cnt * 0.02f;
          c1 = (float)(65535u - znq) * (4.0f / 65535.0f) - 3.0f;
          c2 = (float)zxq * (4.0f / 65535.0f) - 3.0f;
          c3 = (float)ivq * (1.0f / 65535.0f);
        }
        v[0] = (_Float16)c0; v[1] = (_Float16)c1;
        v[2] = (_Float16)c2; v[3] = (_Float16)c3;
      }
      *(half4*)&s_in[(size_t)t * 4] = v;
    }
  } else {
    const _Float16* fin = (const _Float16*)in;       // [b][y][x][CI]
    for (int t = threadIdx.x; t < NCELL; t += 256) {
      int col = t % NCOL;
      int row = t / NCOL;
      int gy = y0 - 1 + row, gx = x0 - 1 + col;
      bool okc = (gy >= 0 && gy < HWI && gx >= 0 && gx < HWI);
      int swz = (CIp == 8) ? 0 : ((CIp == 16) ? ((col >> 2) & 1) : ((col >> 1) & 3));
      #pragma unroll
      for (int c8 = 0; c8 < CIp / 8; ++c8) {
        half8 v = zv;
        if (okc)
          v = *(const half8*)((const _Float16*)fin +
                (((size_t)b * HWI + gy) * HWI + gx) * CI + c8 * 8);
        *(half8*)&s_in[(size_t)t * CIp + ((c8 ^ swz) << 3)] = v;
      }
    }
  }
  // ---- stage weights
  if constexpr (INMODE == 0) {
    // k = p*8+j: j<4 -> tap tA(p), ci=j; j>=4 -> tap tA(p)+1 (even p<6) else 0
    for (int t = threadIdx.x; t < COp * KS * 32; t += 256) {
      int k   = t % (KS * 32);
      int col = t / (KS * 32);
      int cog = cobase + col;
      int p = k >> 3, j = k & 7;
      float v = 0.f;
      if (p < 6 && cog < COT) {
        int tA = p + ((p + 1) >> 1);
        int ci = j & 3;
        if (j < 4) v = wgt[((size_t)cog * CI + ci) * 9 + tA];
        else if ((p & 1) == 0) v = wgt[((size_t)cog * CI + ci) * 9 + tA + 1];
      }
      s_w[col * WROW + k] = (_Float16)v;
    }
  } else {
    for (int t = threadIdx.x; t < COp * KS * 32; t += 256) {
      int k   = t % (KS * 32);
      int col = t / (KS * 32);
      int cog = cobase + col;
      float v = 0.f;
      if (k < KTOT && cog < COT) {
        int tap = k / CIp, ci = k % CIp;
        if (ci < CI) v = wgt[((size_t)cog * CI + ci) * 9 + tap];
      }
      s_w[col * WROW + k] = (_Float16)v;
    }
  }
  if (threadIdx.x < COp) {
    int col = threadIdx.x;
    int cog = cobase + col;
    float sc = 0.f, sh = 0.f;
    if (cog < COT) {
      sc = gam[cog] / sqrtf(var[cog] + 1e-5f);
      sh = (bias[cog] - mean[cog]) * sc + bet[cog];
    }
    s_scale[col] = sc; s_shift[col] = sh;
  }
  __syncthreads();

  const int lane = threadIdx.x & 63;
  const int w    = threadIdx.x >> 6;   // wave 0..3, owns y-rows w*4..w*4+3
  const int m    = lane & 15;
  const int hi   = lane >> 4;

  f32x4 acc[4][XH][NT];
  #pragma unroll
  for (int r = 0; r < 4; ++r)
    #pragma unroll
    for (int h = 0; h < XH; ++h)
      #pragma unroll
      for (int n = 0; n < NT; ++n) acc[r][h][n] = 0.f;

  const int y0w = w * 4;
  #pragma unroll
  for (int ks = 0; ks < KS; ++ks) {
    int aoff;
    if constexpr (INMODE == 0) {
      int p   = ks * 4 + hi;
      int lt  = (p < 6);
      int dy  = lt ? (p >> 1) : 0;
      int dxb = lt ? ((p & 1) << 1) : 0;
      aoff = ((y0w + dy) * NCOL + m + dxb) * CIp;
    } else {
      int kc  = ks * 32 + (hi << 3);
      int tap = kc >> L2C;
      if (tap > 8) tap = 8;               // pad region: real data * zero weight
      int ci  = kc & (CIp - 1);
      int dy  = (tap * 11) >> 5;          // tap/3 for tap in [0,8]
      int dx  = tap - 3 * dy;
      int colA  = m + dx;
      int chunk = ci >> 3;
      int swz = (CIp == 8) ? 0 : ((CIp == 16) ? ((colA >> 2) & 1) : ((colA >> 1) & 3));
      aoff = ((y0w + dy) * NCOL + colA) * CIp + ((chunk ^ swz) << 3);
    }
    const int boff = m * WROW + ks * 32 + (hi << 3);
    half8 bfr[NT];
    #pragma unroll
    for (int n = 0; n < NT; ++n)
      bfr[n] = *(const half8*)&s_w[boff + n * 16 * WROW];
    #pragma unroll
    for (int r = 0; r < 4; ++r) {
      half8 afr[XH];
      #pragma unroll
      for (int h = 0; h < XH; ++h)
        afr[h] = *(const half8*)&s_in[aoff + r * NCOL * CIp + h * 16 * CIp];
      #pragma unroll
      for (int h = 0; h < XH; ++h)
        #pragma unroll
        for (int n = 0; n < NT; ++n)
          acc[r][h][n] = __builtin_amdgcn_mfma_f32_16x16x32_f16(
              afr[h], bfr[n], acc[r][h][n], 0, 0, 0);
    }
  }

  __syncthreads();                       // all LDS reads done; overlay s_in

  if constexpr (POOL) {
    // lane holds conv x = hi*4+q at y-row r; pool x-pairs in-lane, y-pairs
    // across r. Pooled yp = w*2+rp, xp = h*8+hi*2+{0,1}.
    _Float16* s_o = (_Float16*)s_raw;    // [yp][xp][COp] f16
    #pragma unroll
    for (int n = 0; n < NT; ++n) {
      int col = n * 16 + m;
      float sc = s_scale[col], sh = s_shift[col];
      #pragma unroll
      for (int rp = 0; rp < 2; ++rp) {
        #pragma unroll
        for (int h = 0; h < XH; ++h) {
          f32x4 p0 = acc[rp * 2][h][n];
          f32x4 p1 = acc[rp * 2 + 1][h][n];
          float v0 = fmaxf(fmaxf(p0[0], p0[1]), fmaxf(p1[0], p1[1]));
          float v1 = fmaxf(fmaxf(p0[2], p0[3]), fmaxf(p1[2], p1[3]));
          v0 = fmaxf(v0 * sc + sh, 0.f);
          v1 = fmaxf(v1 * sc + sh, 0.f);
          int yp = w * 2 + rp;
          int xp = h * 8 + hi * 2;
          s_o[(yp * PXH + xp) * COp + col]     = (_Float16)v0;
          s_o[(yp * PXH + xp + 1) * COp + col] = (_Float16)v1;
        }
      }
    }
    __syncthreads();
    constexpr int HWO = HWI / 2;
    constexpr int NCH = COT / 8;
    constexpr int NCHG = (COR + 7) / 8;  // 8-chunks this group writes
    _Float16* og = (_Float16*)outv;      // [b][HWO][HWO][COT]
    for (int t = threadIdx.x; t < 8 * PXH * NCHG; t += 256) {
      int c8  = t % NCHG;
      int rem = t / NCHG;
      int xp  = rem % PXH;
      int yp  = rem / PXH;
      half8 v = *(const half8*)&s_o[(yp * PXH + xp) * COp + c8 * 8];
      *(half8*)&og[(((size_t)b * HWO + (y0 / 2 + yp)) * HWO + (x0 / 2 + xp)) * COT
                   + cobase + c8 * 8] = v;
    }
    (void)NCH;
  } else {
    // final layer: NCHW f32 out; 4 rounds staging one y-row per wave
    constexpr int OCS = 66;
    float* s_out = (float*)s_raw;
    float* og = (float*)outv;
    #pragma unroll
    for (int r = 0; r < 4; ++r) {
      if (r) __syncthreads();
      #pragma unroll
      for (int n = 0; n < NT; ++n) {
        int col = n * 16 + m;
        float sc = s_scale[col], sh = s_shift[col];
        f32x4 p = acc[r][0][n];
        #pragma unroll
        for (int q = 0; q < 4; ++q) {
          float v = fmaxf(p[q] * sc + sh, 0.f);
          s_out[col * OCS + w * 16 + hi * 4 + q] = v;
        }
      }
      __syncthreads();
      for (int t = threadIdx.x; t < COR * 4 * 16; t += 256) {
        int xp = t & 15, ws2 = (t >> 4) & 3, col = t >> 6;
        og[(((size_t)b * COT + cobase + col) * HWI + (y0 + ws2 * 4 + r)) * HWI + (x0 + xp)]
          = s_out[col * OCS + ws2 * 16 + xp];
      }
    }
  }
}

extern "C" void kernel_launch(void* const* d_in, const int* in_sizes, int n_in,
                              void* d_out, int out_size, void* d_ws, size_t ws_size,
                              hipStream_t stream) {
  const float* pts = (const float*)d_in[0];
  const int npts = in_sizes[0] / 5;

  const float* w1  = (const float*)d_in[2];
  const float* b1  = (const float*)d_in[3];
  const float* g1  = (const float*)d_in[4];
  const float* be1 = (const float*)d_in[5];
  const float* m1  = (const float*)d_in[6];
  const float* v1  = (const float*)d_in[7];
  const float* w2  = (const float*)d_in[8];
  const float* b2  = (const float*)d_in[9];
  const float* g2  = (const float*)d_in[10];
  const float* be2 = (const float*)d_in[11];
  const float* m2  = (const float*)d_in[12];
  const float* v2  = (const float*)d_in[13];
  const float* w3  = (const float*)d_in[14];
  const float* b3  = (const float*)d_in[15];
  const float* g3  = (const float*)d_in[16];
  const float* be3 = (const float*)d_in[17];
  const float* m3  = (const float*)d_in[18];
  const float* v3  = (const float*)d_in[19];
  const float* w4  = (const float*)d_in[20];
  const float* b4  = (const float*)d_in[21];
  const float* g4  = (const float*)d_in[22];
  const float* be4 = (const float*)d_in[23];
  const float* m4  = (const float*)d_in[24];
  const float* v4  = (const float*)d_in[25];

  char* ws = (char*)d_ws;
  // Workspace (bytes):
  //   packed cells [0, 32M)
  //   l1 [32M, 48M):  f16 CL (4,512,512,8)
  //   l2 [48M, 56.4M): f16 CL (4,256,256,16)
  //   l3 [56.4M, 60.6M): f16 CL (4,128,128,32)
  ull* packed = (ull*)ws;
  void* l1 = (void*)(ws + 33554432);
  void* l2 = (void*)(ws + 50331648);
  void* l3 = (void*)(ws + 58720256);
  void* outp = d_out;

  clear_cells<<<2048, 256, 0, stream>>>((float4*)packed, (int)((size_t)NB * HH * WW * 8 / 16));
  scatter_points_packed<<<(npts + 255) / 256, 256, 0, stream>>>(pts, npts, packed);

  // <CI, CIp, COT, COp, HWI, PXT, KS, POOL, INMODE, OUTCL>
  conv_mfma<4,  4,  8,  16, 1024, 64, 2, true,  0, true ><<<dim3(1024, 1, 4), 256, 0, stream>>>(packed, l1, w1, b1, g1, be1, m1, v1);
  conv_mfma<8,  8,  16, 16, 512,  64, 3, true,  1, true ><<<dim3(256,  1, 4), 256, 0, stream>>>(l1,  l2, w2, b2, g2, be2, m2, v2);
  conv_mfma<16, 16, 32, 16, 256,  32, 5, true,  1, true ><<<dim3(128,  2, 4), 256, 0, stream>>>(l2,  l3, w3, b3, g3, be3, m3, v3);
  conv_mfma<32, 32, 64, 16, 128,  16, 9, false, 1, false><<<dim3(64,   4, 4), 256, 0, stream>>>(l3, outp, w4, b4, g4, be4, m4, v4);
}

// Round 9
// 108.879 us; speedup vs baseline: 1.3852x; 1.3852x over previous
//
#include <hip/hip_runtime.h>
#include <cstdint>
#include <cstddef>

#define HH 1024
#define WW 1024
#define NB 4

typedef _Float16 half8 __attribute__((ext_vector_type(8)));
typedef float f32x4 __attribute__((ext_vector_type(4)));
typedef unsigned long long ull;

// ---------------------------------------------------------------------------
// Fast clear for the 32 MB packed-cell buffer (~5.5 TB/s).
// ---------------------------------------------------------------------------
__global__ __launch_bounds__(256)
void clear_cells(float4* __restrict__ p, int n4) {
  int stride = gridDim.x * blockDim.x;
  float4 z; z.x = 0.f; z.y = 0.f; z.z = 0.f; z.w = 0.f;
  for (int i = blockIdx.x * blockDim.x + threadIdx.x; i < n4; i += stride)
    p[i] = z;
}

// ---------------------------------------------------------------------------
// Scatter: 4 per-cell stats packed in ONE u64 updated by CAS.
//   [63:48] zmax_q16 | [47:32] 65535-zmin_q16 | [31:16] iv_q16 | [15:0] cnt
// All-zero word == empty cell. Optimistic first CAS (~90% one-shot).
// ---------------------------------------------------------------------------
__device__ __forceinline__ ull merge_cell(ull a, unsigned zq, unsigned zn, unsigned iq) {
  unsigned cnt = (unsigned)(a & 0xFFFFull);
  unsigned civ = (unsigned)((a >> 16) & 0xFFFFull);
  unsigned czn = (unsigned)((a >> 32) & 0xFFFFull);
  unsigned czx = (unsigned)(a >> 48);
  cnt = (cnt < 65535u) ? cnt + 1u : cnt;
  civ = civ > iq ? civ : iq;
  czn = czn > zn ? czn : zn;
  czx = czx > zq ? czx : zq;
  return (ull)cnt | ((ull)civ << 16) | ((ull)czn << 32) | ((ull)czx << 48);
}

__global__ __launch_bounds__(256)
void scatter_points_packed(const float* __restrict__ pts, int n,
                           ull* __restrict__ cell) {
  const float xs   = (float)(1024.0 / 69.12);
  const float ys   = (float)(1024.0 / (39.68 + 39.68));
  const float yoff = 39.68f;
  int i = blockIdx.x * blockDim.x + threadIdx.x;
  if (i >= n) return;
  float b  = pts[(size_t)i * 5 + 0];
  float x  = pts[(size_t)i * 5 + 1];
  float y  = pts[(size_t)i * 5 + 2];
  float z  = pts[(size_t)i * 5 + 3];
  float it = pts[(size_t)i * 5 + 4];
  int xp = (int)(x * xs);                 // trunc toward zero == astype(int32)
  int yp = (int)((y + yoff) * ys);
  if (xp < 0 || xp >= WW || yp < 0 || yp >= HH) return;
  int lin = ((int)b * HH + yp) * WW + xp;

  float zc = fminf(fmaxf(z, -3.f), 1.f);
  unsigned zq = (unsigned)(int)((zc + 3.f) * (65535.f / 4.f) + 0.5f);
  if (zq > 65535u) zq = 65535u;
  float ic = fminf(fmaxf(it, 0.f), 1.f);
  unsigned iq = (unsigned)(int)(ic * 65535.f + 0.5f);
  if (iq > 65535u) iq = 65535u;
  unsigned zn = 65535u - zq;

  ull g = atomicCAS(&cell[lin], 0ull, merge_cell(0ull, zq, zn, iq));
  while (g != 0ull) {
    ull r = atomicCAS(&cell[lin], g, merge_cell(g, zq, zn, iq));
    if (r == g) break;
    g = r;
  }
}

// ---------------------------------------------------------------------------
// Implicit-GEMM conv3x3 + bias + BN + ReLU (+2x2 maxpool) via MFMA f16.
// Per block: 16 y-rows x PXT x-cols, co group [cobase, cobase+COp).
// INMODE 0: packed-u64 BEV input (CIp=8, 4 real ci + 4 zero pad).
// INMODE 1: channels-last f16 [b][y][x][CI], k = tap*CIp+ci.
// OUTCL: true = channels-last f16 out; false = NCHW f32 (final layer).
// NOTE: LDS A-fragment loads must stay 16B-aligned (cell stride multiple of
// 8 f16) or ds_read_b128 scalarizes — R8's CIp=4 packing cost 3x (72us).
// ---------------------------------------------------------------------------
template<int CI, int CIp, int COT, int COp, int HWI, int PXT, int KS,
         bool POOL, int INMODE, bool OUTCL>
__global__ __launch_bounds__(256)
void conv_mfma(const void* __restrict__ in, void* __restrict__ outv,
               const float* __restrict__ wgt, const float* __restrict__ bias,
               const float* __restrict__ gam, const float* __restrict__ bet,
               const float* __restrict__ mean, const float* __restrict__ var) {
  constexpr int PYT  = 16;
  constexpr int NT   = COp / 16;
  constexpr int XH   = PXT / 16;
  constexpr int NCOL = PXT + 2;
  constexpr int NCELL = (PYT + 2) * NCOL;
  constexpr int WROW = KS * 32 + 8;
  constexpr int INE  = NCELL * CIp;
  constexpr int L2C  = (CIp == 8) ? 3 : ((CIp == 16) ? 4 : 5);
  constexpr int KTOT = 9 * CIp;
  constexpr int COR  = (COT < COp) ? COT : COp;
  constexpr int PXH  = PXT / 2;
  static_assert(CIp % 8 == 0 && COp % 16 == 0, "");
  static_assert(!OUTCL || (POOL && COT % 8 == 0), "");
  static_assert(!POOL || 8 * PXH * COp * 2 <= INE * 2, "out overlay fits");
  static_assert(POOL || COp * 66 * 4 <= INE * 2, "out overlay fits");

  __shared__ __align__(16) char s_raw[INE * 2 + COp * WROW * 2 + COp * 8];
  _Float16* s_in = (_Float16*)s_raw;
  _Float16* s_w  = (_Float16*)(s_raw + INE * 2);
  float* s_scale = (float*)(s_raw + INE * 2 + (size_t)COp * WROW * 2);
  float* s_shift = s_scale + COp;

  const int cobase = blockIdx.y * COp;
  const int b = blockIdx.z;
  constexpr int NPX = HWI / PXT;
  const int pyi = blockIdx.x / NPX;
  const int pxi = blockIdx.x - pyi * NPX;
  const int y0 = pyi * PYT, x0 = pxi * PXT;

  half8 zv;
  #pragma unroll
  for (int q = 0; q < 8; ++q) zv[q] = (_Float16)0.f;

  // ---- stage input patch (one cell per iteration; all ci vectorized)
  if constexpr (INMODE == 0) {
    const ull* pin = (const ull*)in;
    for (int t = threadIdx.x; t < NCELL; t += 256) {
      int col = t % NCOL;
      int row = t / NCOL;
      int gy = y0 - 1 + row, gx = x0 - 1 + col;
      half8 v = zv;                                  // halo: zeros
      if (gy >= 0 && gy < HH && gx >= 0 && gx < WW) {
        ull pv = pin[((size_t)b * HH + gy) * WW + gx];
        unsigned cnt = (unsigned)(pv & 0xFFFFull);
        unsigned ivq = (unsigned)((pv >> 16) & 0xFFFFull);
        unsigned znq = (unsigned)((pv >> 32) & 0xFFFFull);
        unsigned zxq = (unsigned)(pv >> 48);
        float c0, c1, c2, c3;
        if (cnt == 0) { c0 = 0.02f; c1 = 10.f; c2 = -10.f; c3 = 0.f; }
        else {
          c0 = (float)cnt * 0.02f;
          c1 = (float)(65535u - znq) * (4.0f / 65535.0f) - 3.0f;
          c2 = (float)zxq * (4.0f / 65535.0f) - 3.0f;
          c3 = (float)ivq * (1.0f / 65535.0f);
        }
        v[0] = (_Float16)c0; v[1] = (_Float16)c1;
        v[2] = (_Float16)c2; v[3] = (_Float16)c3;
      }
      *(half8*)&s_in[(size_t)t * CIp] = v;           // CIp==8, swz==0
    }
  } else {
    const _Float16* fin = (const _Float16*)in;       // [b][y][x][CI]
    for (int t = threadIdx.x; t < NCELL; t += 256) {
      int col = t % NCOL;
      int row = t / NCOL;
      int gy = y0 - 1 + row, gx = x0 - 1 + col;
      bool okc = (gy >= 0 && gy < HWI && gx >= 0 && gx < HWI);
      int swz = (CIp == 8) ? 0 : ((CIp == 16) ? ((col >> 2) & 1) : ((col >> 1) & 3));
      #pragma unroll
      for (int c8 = 0; c8 < CIp / 8; ++c8) {
        half8 v = zv;
        if (okc)
          v = *(const half8*)((const _Float16*)fin +
                (((size_t)b * HWI + gy) * HWI + gx) * CI + c8 * 8);
        *(half8*)&s_in[(size_t)t * CIp + ((c8 ^ swz) << 3)] = v;
      }
    }
  }
  // ---- stage weights (this group's co only), reordered [co][tap*CIp+ci]
  for (int t = threadIdx.x; t < COp * KS * 32; t += 256) {
    int k   = t % (KS * 32);
    int col = t / (KS * 32);
    int cog = cobase + col;
    float v = 0.f;
    if (k < KTOT && cog < COT) {
      int tap = k / CIp, ci = k % CIp;
      if (ci < CI) v = wgt[((size_t)cog * CI + ci) * 9 + tap];
    }
    s_w[col * WROW + k] = (_Float16)v;
  }
  if (threadIdx.x < COp) {
    int col = threadIdx.x;
    int cog = cobase + col;
    float sc = 0.f, sh = 0.f;
    if (cog < COT) {
      sc = gam[cog] / sqrtf(var[cog] + 1e-5f);
      sh = (bias[cog] - mean[cog]) * sc + bet[cog];
    }
    s_scale[col] = sc; s_shift[col] = sh;
  }
  __syncthreads();

  const int lane = threadIdx.x & 63;
  const int w    = threadIdx.x >> 6;   // wave 0..3, owns y-rows w*4..w*4+3
  const int m    = lane & 15;
  const int hi   = lane >> 4;

  f32x4 acc[4][XH][NT];
  #pragma unroll
  for (int r = 0; r < 4; ++r)
    #pragma unroll
    for (int h = 0; h < XH; ++h)
      #pragma unroll
      for (int n = 0; n < NT; ++n) acc[r][h][n] = 0.f;

  const int y0w = w * 4;
  #pragma unroll
  for (int ks = 0; ks < KS; ++ks) {
    int kc  = ks * 32 + (hi << 3);
    int tap = kc >> L2C;
    if (tap > 8) tap = 8;                 // pad region: real data * zero weight
    int ci  = kc & (CIp - 1);
    int dy  = (tap * 11) >> 5;            // tap/3 for tap in [0,8]
    int dx  = tap - 3 * dy;
    int colA  = m + dx;
    int chunk = ci >> 3;
    int swz = (CIp == 8) ? 0 : ((CIp == 16) ? ((colA >> 2) & 1) : ((colA >> 1) & 3));
    int aoff = ((y0w + dy) * NCOL + colA) * CIp + ((chunk ^ swz) << 3);
    const int boff = m * WROW + ks * 32 + (hi << 3);
    half8 bfr[NT];
    #pragma unroll
    for (int n = 0; n < NT; ++n)
      bfr[n] = *(const half8*)&s_w[boff + n * 16 * WROW];
    #pragma unroll
    for (int r = 0; r < 4; ++r) {
      half8 afr[XH];
      #pragma unroll
      for (int h = 0; h < XH; ++h)
        afr[h] = *(const half8*)&s_in[aoff + r * NCOL * CIp + h * 16 * CIp];
      #pragma unroll
      for (int h = 0; h < XH; ++h)
        #pragma unroll
        for (int n = 0; n < NT; ++n)
          acc[r][h][n] = __builtin_amdgcn_mfma_f32_16x16x32_f16(
              afr[h], bfr[n], acc[r][h][n], 0, 0, 0);
    }
  }

  __syncthreads();                       // all LDS reads done; overlay s_in

  if constexpr (POOL) {
    // lane holds conv x = hi*4+q at y-row r; pool x-pairs in-lane, y-pairs
    // across r. Pooled yp = w*2+rp, xp = h*8+hi*2+{0,1}.
    _Float16* s_o = (_Float16*)s_raw;    // [yp][xp][COp] f16
    #pragma unroll
    for (int n = 0; n < NT; ++n) {
      int col = n * 16 + m;
      float sc = s_scale[col], sh = s_shift[col];
      #pragma unroll
      for (int rp = 0; rp < 2; ++rp) {
        #pragma unroll
        for (int h = 0; h < XH; ++h) {
          f32x4 p0 = acc[rp * 2][h][n];
          f32x4 p1 = acc[rp * 2 + 1][h][n];
          float v0 = fmaxf(fmaxf(p0[0], p0[1]), fmaxf(p1[0], p1[1]));
          float v1 = fmaxf(fmaxf(p0[2], p0[3]), fmaxf(p1[2], p1[3]));
          v0 = fmaxf(v0 * sc + sh, 0.f);
          v1 = fmaxf(v1 * sc + sh, 0.f);
          int yp = w * 2 + rp;
          int xp = h * 8 + hi * 2;
          s_o[(yp * PXH + xp) * COp + col]     = (_Float16)v0;
          s_o[(yp * PXH + xp + 1) * COp + col] = (_Float16)v1;
        }
      }
    }
    __syncthreads();
    constexpr int HWO = HWI / 2;
    constexpr int NCHG = (COR + 7) / 8;  // 8-chunks this group writes
    _Float16* og = (_Float16*)outv;      // [b][HWO][HWO][COT]
    for (int t = threadIdx.x; t < 8 * PXH * NCHG; t += 256) {
      int c8  = t % NCHG;
      int rem = t / NCHG;
      int xp  = rem % PXH;
      int yp  = rem / PXH;
      half8 v = *(const half8*)&s_o[(yp * PXH + xp) * COp + c8 * 8];
      *(half8*)&og[(((size_t)b * HWO + (y0 / 2 + yp)) * HWO + (x0 / 2 + xp)) * COT
                   + cobase + c8 * 8] = v;
    }
  } else {
    // final layer: NCHW f32 out; 4 rounds staging one y-row per wave
    constexpr int OCS = 66;
    float* s_out = (float*)s_raw;
    float* og = (float*)outv;
    #pragma unroll
    for (int r = 0; r < 4; ++r) {
      if (r) __syncthreads();
      #pragma unroll
      for (int n = 0; n < NT; ++n) {
        int col = n * 16 + m;
        float sc = s_scale[col], sh = s_shift[col];
        f32x4 p = acc[r][0][n];
        #pragma unroll
        for (int q = 0; q < 4; ++q) {
          float v = fmaxf(p[q] * sc + sh, 0.f);
          s_out[col * OCS + w * 16 + hi * 4 + q] = v;
        }
      }
      __syncthreads();
      for (int t = threadIdx.x; t < COR * 4 * 16; t += 256) {
        int xp = t & 15, ws2 = (t >> 4) & 3, col = t >> 6;
        og[(((size_t)b * COT + cobase + col) * HWI + (y0 + ws2 * 4 + r)) * HWI + (x0 + xp)]
          = s_out[col * OCS + ws2 * 16 + xp];
      }
    }
  }
}

extern "C" void kernel_launch(void* const* d_in, const int* in_sizes, int n_in,
                              void* d_out, int out_size, void* d_ws, size_t ws_size,
                              hipStream_t stream) {
  const float* pts = (const float*)d_in[0];
  const int npts = in_sizes[0] / 5;

  const float* w1  = (const float*)d_in[2];
  const float* b1  = (const float*)d_in[3];
  const float* g1  = (const float*)d_in[4];
  const float* be1 = (const float*)d_in[5];
  const float* m1  = (const float*)d_in[6];
  const float* v1  = (const float*)d_in[7];
  const float* w2  = (const float*)d_in[8];
  const float* b2  = (const float*)d_in[9];
  const float* g2  = (const float*)d_in[10];
  const float* be2 = (const float*)d_in[11];
  const float* m2  = (const float*)d_in[12];
  const float* v2  = (const float*)d_in[13];
  const float* w3  = (const float*)d_in[14];
  const float* b3  = (const float*)d_in[15];
  const float* g3  = (const float*)d_in[16];
  const float* be3 = (const float*)d_in[17];
  const float* m3  = (const float*)d_in[18];
  const float* v3  = (const float*)d_in[19];
  const float* w4  = (const float*)d_in[20];
  const float* b4  = (const float*)d_in[21];
  const float* g4  = (const float*)d_in[22];
  const float* be4 = (const float*)d_in[23];
  const float* m4  = (const float*)d_in[24];
  const float* v4  = (const float*)d_in[25];

  char* ws = (char*)d_ws;
  // Workspace (bytes):
  //   packed cells [0, 32M)
  //   l1 [32M, 48M):  f16 CL (4,512,512,8)
  //   l2 [48M, 56.4M): f16 CL (4,256,256,16)
  //   l3 [56.4M, 60.6M): f16 CL (4,128,128,32)
  ull* packed = (ull*)ws;
  void* l1 = (void*)(ws + 33554432);
  void* l2 = (void*)(ws + 50331648);
  void* l3 = (void*)(ws + 58720256);
  void* outp = d_out;

  clear_cells<<<2048, 256, 0, stream>>>((float4*)packed, (int)((size_t)NB * HH * WW * 8 / 16));
  scatter_points_packed<<<(npts + 255) / 256, 256, 0, stream>>>(pts, npts, packed);

  // <CI, CIp, COT, COp, HWI, PXT, KS, POOL, INMODE, OUTCL>
  conv_mfma<4,  8,  8,  16, 1024, 64, 3, true,  0, true ><<<dim3(1024, 1, 4), 256, 0, stream>>>(packed, l1, w1, b1, g1, be1, m1, v1);
  conv_mfma<8,  8,  16, 16, 512,  64, 3, true,  1, true ><<<dim3(256,  1, 4), 256, 0, stream>>>(l1,  l2, w2, b2, g2, be2, m2, v2);
  conv_mfma<16, 16, 32, 16, 256,  32, 5, true,  1, true ><<<dim3(128,  2, 4), 256, 0, stream>>>(l2,  l3, w3, b3, g3, be3, m3, v3);
  conv_mfma<32, 32, 64, 16, 128,  16, 9, false, 1, false><<<dim3(64,   4, 4), 256, 0, stream>>>(l3, outp, w4, b4, g4, be4, m4, v4);
}

// Round 10
// 107.217 us; speedup vs baseline: 1.4067x; 1.0155x over previous
//
#include <hip/hip_runtime.h>
#include <cstdint>
#include <cstddef>

#define HH 1024
#define WW 1024
#define NB 4

typedef _Float16 half8 __attribute__((ext_vector_type(8)));
typedef float f32x4 __attribute__((ext_vector_type(4)));
typedef unsigned long long ull;

// ---------------------------------------------------------------------------
// Fast clear for the 16 MB packed-cell buffer (~5.5 TB/s).
// ---------------------------------------------------------------------------
__global__ __launch_bounds__(256)
void clear_cells(float4* __restrict__ p, int n4) {
  int stride = gridDim.x * blockDim.x;
  float4 z; z.x = 0.f; z.y = 0.f; z.z = 0.f; z.w = 0.f;
  for (int i = blockIdx.x * blockDim.x + threadIdx.x; i < n4; i += stride)
    p[i] = z;
}

// ---------------------------------------------------------------------------
// Scatter: 4 per-cell stats packed in ONE u32 updated by CAS.
//   [31:24] zmax_q8 | [23:16] 255-zmin_q8 | [15:8] iv_q8 | [7:0] cnt (sat 255)
// All-zero word == empty cell (occupied => cnt>=1). 8-bit z/iv quantization
// (err <= 0.008 / 0.002) is far inside the 0.415 absmax budget.
// 16 cells/64B-line halves the random-RMW line traffic vs u64 cells.
// ---------------------------------------------------------------------------
__device__ __forceinline__ unsigned merge_cell(unsigned a, unsigned zq,
                                               unsigned zn, unsigned iq) {
  unsigned cnt = a & 0xFFu;
  unsigned civ = (a >> 8) & 0xFFu;
  unsigned czn = (a >> 16) & 0xFFu;
  unsigned czx = a >> 24;
  cnt = (cnt < 255u) ? cnt + 1u : cnt;
  civ = civ > iq ? civ : iq;
  czn = czn > zn ? czn : zn;
  czx = czx > zq ? czx : zq;
  return cnt | (civ << 8) | (czn << 16) | (czx << 24);
}

__global__ __launch_bounds__(256)
void scatter_points_packed(const float* __restrict__ pts, int n,
                           unsigned* __restrict__ cell) {
  const float xs   = (float)(1024.0 / 69.12);
  const float ys   = (float)(1024.0 / (39.68 + 39.68));
  const float yoff = 39.68f;
  int i = blockIdx.x * blockDim.x + threadIdx.x;
  if (i >= n) return;
  float b  = pts[(size_t)i * 5 + 0];
  float x  = pts[(size_t)i * 5 + 1];
  float y  = pts[(size_t)i * 5 + 2];
  float z  = pts[(size_t)i * 5 + 3];
  float it = pts[(size_t)i * 5 + 4];
  int xp = (int)(x * xs);                 // trunc toward zero == astype(int32)
  int yp = (int)((y + yoff) * ys);
  if (xp < 0 || xp >= WW || yp < 0 || yp >= HH) return;
  int lin = ((int)b * HH + yp) * WW + xp;

  float zc = fminf(fmaxf(z, -3.f), 1.f);
  unsigned zq = (unsigned)(int)((zc + 3.f) * (255.f / 4.f) + 0.5f);
  if (zq > 255u) zq = 255u;
  float ic = fminf(fmaxf(it, 0.f), 1.f);
  unsigned iq = (unsigned)(int)(ic * 255.f + 0.5f);
  if (iq > 255u) iq = 255u;
  unsigned zn = 255u - zq;

  unsigned g = atomicCAS(&cell[lin], 0u, merge_cell(0u, zq, zn, iq));
  while (g != 0u) {
    unsigned r = atomicCAS(&cell[lin], g, merge_cell(g, zq, zn, iq));
    if (r == g) break;
    g = r;
  }
}

// ---------------------------------------------------------------------------
// Implicit-GEMM conv3x3 + bias + BN + ReLU (+2x2 maxpool) via MFMA f16.
// Per block: 16 y-rows x PXT x-cols, co group [cobase, cobase+COp).
// INMODE 0: packed-u32 BEV input (CIp=8, 4 real ci + 4 zero pad).
// INMODE 1: channels-last f16 [b][y][x][CI], k = tap*CIp+ci.
// OUTCL: true = channels-last f16 out; false = NCHW f32 (final layer).
// NOTE: LDS A-fragment loads must stay 16B-aligned (cell stride multiple of
// 8 f16) or ds_read_b128 scalarizes — R8's CIp=4 packing cost 3x (72us).
// ---------------------------------------------------------------------------
template<int CI, int CIp, int COT, int COp, int HWI, int PXT, int KS,
         bool POOL, int INMODE, bool OUTCL>
__global__ __launch_bounds__(256)
void conv_mfma(const void* __restrict__ in, void* __restrict__ outv,
               const float* __restrict__ wgt, const float* __restrict__ bias,
               const float* __restrict__ gam, const float* __restrict__ bet,
               const float* __restrict__ mean, const float* __restrict__ var) {
  constexpr int PYT  = 16;
  constexpr int NT   = COp / 16;
  constexpr int XH   = PXT / 16;
  constexpr int NCOL = PXT + 2;
  constexpr int NCELL = (PYT + 2) * NCOL;
  constexpr int WROW = KS * 32 + 8;
  constexpr int INE  = NCELL * CIp;
  constexpr int L2C  = (CIp == 8) ? 3 : ((CIp == 16) ? 4 : 5);
  constexpr int KTOT = 9 * CIp;
  constexpr int COR  = (COT < COp) ? COT : COp;
  constexpr int PXH  = PXT / 2;
  static_assert(CIp % 8 == 0 && COp % 16 == 0, "");
  static_assert(!OUTCL || (POOL && COT % 8 == 0), "");
  static_assert(!POOL || 8 * PXH * COp * 2 <= INE * 2, "out overlay fits");
  static_assert(POOL || COp * 66 * 4 <= INE * 2, "out overlay fits");

  __shared__ __align__(16) char s_raw[INE * 2 + COp * WROW * 2 + COp * 8];
  _Float16* s_in = (_Float16*)s_raw;
  _Float16* s_w  = (_Float16*)(s_raw + INE * 2);
  float* s_scale = (float*)(s_raw + INE * 2 + (size_t)COp * WROW * 2);
  float* s_shift = s_scale + COp;

  const int cobase = blockIdx.y * COp;
  const int b = blockIdx.z;
  constexpr int NPX = HWI / PXT;
  const int pyi = blockIdx.x / NPX;
  const int pxi = blockIdx.x - pyi * NPX;
  const int y0 = pyi * PYT, x0 = pxi * PXT;

  half8 zv;
  #pragma unroll
  for (int q = 0; q < 8; ++q) zv[q] = (_Float16)0.f;

  // ---- stage input patch (one cell per iteration; all ci vectorized)
  if constexpr (INMODE == 0) {
    const unsigned* pin = (const unsigned*)in;
    for (int t = threadIdx.x; t < NCELL; t += 256) {
      int col = t % NCOL;
      int row = t / NCOL;
      int gy = y0 - 1 + row, gx = x0 - 1 + col;
      half8 v = zv;                                  // halo: zeros
      if (gy >= 0 && gy < HH && gx >= 0 && gx < WW) {
        unsigned pv = pin[((size_t)b * HH + gy) * WW + gx];
        unsigned cnt = pv & 0xFFu;
        unsigned ivq = (pv >> 8) & 0xFFu;
        unsigned znq = (pv >> 16) & 0xFFu;
        unsigned zxq = pv >> 24;
        float c0, c1, c2, c3;
        if (cnt == 0) { c0 = 0.02f; c1 = 10.f; c2 = -10.f; c3 = 0.f; }
        else {
          c0 = (float)cnt * 0.02f;
          c1 = (float)(255u - znq) * (4.0f / 255.0f) - 3.0f;
          c2 = (float)zxq * (4.0f / 255.0f) - 3.0f;
          c3 = (float)ivq * (1.0f / 255.0f);
        }
        v[0] = (_Float16)c0; v[1] = (_Float16)c1;
        v[2] = (_Float16)c2; v[3] = (_Float16)c3;
      }
      *(half8*)&s_in[(size_t)t * CIp] = v;           // CIp==8, swz==0
    }
  } else {
    const _Float16* fin = (const _Float16*)in;       // [b][y][x][CI]
    for (int t = threadIdx.x; t < NCELL; t += 256) {
      int col = t % NCOL;
      int row = t / NCOL;
      int gy = y0 - 1 + row, gx = x0 - 1 + col;
      bool okc = (gy >= 0 && gy < HWI && gx >= 0 && gx < HWI);
      int swz = (CIp == 8) ? 0 : ((CIp == 16) ? ((col >> 2) & 1) : ((col >> 1) & 3));
      #pragma unroll
      for (int c8 = 0; c8 < CIp / 8; ++c8) {
        half8 v = zv;
        if (okc)
          v = *(const half8*)((const _Float16*)fin +
                (((size_t)b * HWI + gy) * HWI + gx) * CI + c8 * 8);
        *(half8*)&s_in[(size_t)t * CIp + ((c8 ^ swz) << 3)] = v;
      }
    }
  }
  // ---- stage weights (this group's co only), reordered [co][tap*CIp+ci]
  for (int t = threadIdx.x; t < COp * KS * 32; t += 256) {
    int k   = t % (KS * 32);
    int col = t / (KS * 32);
    int cog = cobase + col;
    float v = 0.f;
    if (k < KTOT && cog < COT) {
      int tap = k / CIp, ci = k % CIp;
      if (ci < CI) v = wgt[((size_t)cog * CI + ci) * 9 + tap];
    }
    s_w[col * WROW + k] = (_Float16)v;
  }
  if (threadIdx.x < COp) {
    int col = threadIdx.x;
    int cog = cobase + col;
    float sc = 0.f, sh = 0.f;
    if (cog < COT) {
      sc = gam[cog] / sqrtf(var[cog] + 1e-5f);
      sh = (bias[cog] - mean[cog]) * sc + bet[cog];
    }
    s_scale[col] = sc; s_shift[col] = sh;
  }
  __syncthreads();

  const int lane = threadIdx.x & 63;
  const int w    = threadIdx.x >> 6;   // wave 0..3, owns y-rows w*4..w*4+3
  const int m    = lane & 15;
  const int hi   = lane >> 4;

  f32x4 acc[4][XH][NT];
  #pragma unroll
  for (int r = 0; r < 4; ++r)
    #pragma unroll
    for (int h = 0; h < XH; ++h)
      #pragma unroll
      for (int n = 0; n < NT; ++n) acc[r][h][n] = 0.f;

  const int y0w = w * 4;
  #pragma unroll
  for (int ks = 0; ks < KS; ++ks) {
    int kc  = ks * 32 + (hi << 3);
    int tap = kc >> L2C;
    if (tap > 8) tap = 8;                 // pad region: real data * zero weight
    int ci  = kc & (CIp - 1);
    int dy  = (tap * 11) >> 5;            // tap/3 for tap in [0,8]
    int dx  = tap - 3 * dy;
    int colA  = m + dx;
    int chunk = ci >> 3;
    int swz = (CIp == 8) ? 0 : ((CIp == 16) ? ((colA >> 2) & 1) : ((colA >> 1) & 3));
    int aoff = ((y0w + dy) * NCOL + colA) * CIp + ((chunk ^ swz) << 3);
    const int boff = m * WROW + ks * 32 + (hi << 3);
    half8 bfr[NT];
    #pragma unroll
    for (int n = 0; n < NT; ++n)
      bfr[n] = *(const half8*)&s_w[boff + n * 16 * WROW];
    #pragma unroll
    for (int r = 0; r < 4; ++r) {
      half8 afr[XH];
      #pragma unroll
      for (int h = 0; h < XH; ++h)
        afr[h] = *(const half8*)&s_in[aoff + r * NCOL * CIp + h * 16 * CIp];
      #pragma unroll
      for (int h = 0; h < XH; ++h)
        #pragma unroll
        for (int n = 0; n < NT; ++n)
          acc[r][h][n] = __builtin_amdgcn_mfma_f32_16x16x32_f16(
              afr[h], bfr[n], acc[r][h][n], 0, 0, 0);
    }
  }

  __syncthreads();                       // all LDS reads done; overlay s_in

  if constexpr (POOL) {
    // lane holds conv x = hi*4+q at y-row r; pool x-pairs in-lane, y-pairs
    // across r. Pooled yp = w*2+rp, xp = h*8+hi*2+{0,1}.
    _Float16* s_o = (_Float16*)s_raw;    // [yp][xp][COp] f16
    #pragma unroll
    for (int n = 0; n < NT; ++n) {
      int col = n * 16 + m;
      float sc = s_scale[col], sh = s_shift[col];
      #pragma unroll
      for (int rp = 0; rp < 2; ++rp) {
        #pragma unroll
        for (int h = 0; h < XH; ++h) {
          f32x4 p0 = acc[rp * 2][h][n];
          f32x4 p1 = acc[rp * 2 + 1][h][n];
          float v0 = fmaxf(fmaxf(p0[0], p0[1]), fmaxf(p1[0], p1[1]));
          float v1 = fmaxf(fmaxf(p0[2], p0[3]), fmaxf(p1[2], p1[3]));
          v0 = fmaxf(v0 * sc + sh, 0.f);
          v1 = fmaxf(v1 * sc + sh, 0.f);
          int yp = w * 2 + rp;
          int xp = h * 8 + hi * 2;
          s_o[(yp * PXH + xp) * COp + col]     = (_Float16)v0;
          s_o[(yp * PXH + xp + 1) * COp + col] = (_Float16)v1;
        }
      }
    }
    __syncthreads();
    constexpr int HWO = HWI / 2;
    constexpr int NCHG = (COR + 7) / 8;  // 8-chunks this group writes
    _Float16* og = (_Float16*)outv;      // [b][HWO][HWO][COT]
    for (int t = threadIdx.x; t < 8 * PXH * NCHG; t += 256) {
      int c8  = t % NCHG;
      int rem = t / NCHG;
      int xp  = rem % PXH;
      int yp  = rem / PXH;
      half8 v = *(const half8*)&s_o[(yp * PXH + xp) * COp + c8 * 8];
      *(half8*)&og[(((size_t)b * HWO + (y0 / 2 + yp)) * HWO + (x0 / 2 + xp)) * COT
                   + cobase + c8 * 8] = v;
    }
  } else {
    // final layer: NCHW f32 out; 4 rounds staging one y-row per wave
    constexpr int OCS = 66;
    float* s_out = (float*)s_raw;
    float* og = (float*)outv;
    #pragma unroll
    for (int r = 0; r < 4; ++r) {
      if (r) __syncthreads();
      #pragma unroll
      for (int n = 0; n < NT; ++n) {
        int col = n * 16 + m;
        float sc = s_scale[col], sh = s_shift[col];
        f32x4 p = acc[r][0][n];
        #pragma unroll
        for (int q = 0; q < 4; ++q) {
          float v = fmaxf(p[q] * sc + sh, 0.f);
          s_out[col * OCS + w * 16 + hi * 4 + q] = v;
        }
      }
      __syncthreads();
      for (int t = threadIdx.x; t < COR * 4 * 16; t += 256) {
        int xp = t & 15, ws2 = (t >> 4) & 3, col = t >> 6;
        og[(((size_t)b * COT + cobase + col) * HWI + (y0 + ws2 * 4 + r)) * HWI + (x0 + xp)]
          = s_out[col * OCS + ws2 * 16 + xp];
      }
    }
  }
}

extern "C" void kernel_launch(void* const* d_in, const int* in_sizes, int n_in,
                              void* d_out, int out_size, void* d_ws, size_t ws_size,
                              hipStream_t stream) {
  const float* pts = (const float*)d_in[0];
  const int npts = in_sizes[0] / 5;

  const float* w1  = (const float*)d_in[2];
  const float* b1  = (const float*)d_in[3];
  const float* g1  = (const float*)d_in[4];
  const float* be1 = (const float*)d_in[5];
  const float* m1  = (const float*)d_in[6];
  const float* v1  = (const float*)d_in[7];
  const float* w2  = (const float*)d_in[8];
  const float* b2  = (const float*)d_in[9];
  const float* g2  = (const float*)d_in[10];
  const float* be2 = (const float*)d_in[11];
  const float* m2  = (const float*)d_in[12];
  const float* v2  = (const float*)d_in[13];
  const float* w3  = (const float*)d_in[14];
  const float* b3  = (const float*)d_in[15];
  const float* g3  = (const float*)d_in[16];
  const float* be3 = (const float*)d_in[17];
  const float* m3  = (const float*)d_in[18];
  const float* v3  = (const float*)d_in[19];
  const float* w4  = (const float*)d_in[20];
  const float* b4  = (const float*)d_in[21];
  const float* g4  = (const float*)d_in[22];
  const float* be4 = (const float*)d_in[23];
  const float* m4  = (const float*)d_in[24];
  const float* v4  = (const float*)d_in[25];

  char* ws = (char*)d_ws;
  // Workspace (bytes):
  //   packed cells [0, 16M): u32 per cell
  //   l1 [32M, 48M):  f16 CL (4,512,512,8)
  //   l2 [48M, 56.4M): f16 CL (4,256,256,16)
  //   l3 [56.4M, 60.6M): f16 CL (4,128,128,32)
  unsigned* packed = (unsigned*)ws;
  void* l1 = (void*)(ws + 33554432);
  void* l2 = (void*)(ws + 50331648);
  void* l3 = (void*)(ws + 58720256);
  void* outp = d_out;

  clear_cells<<<2048, 256, 0, stream>>>((float4*)packed, (int)((size_t)NB * HH * WW * 4 / 16));
  scatter_points_packed<<<(npts + 255) / 256, 256, 0, stream>>>(pts, npts, packed);

  // <CI, CIp, COT, COp, HWI, PXT, KS, POOL, INMODE, OUTCL>
  conv_mfma<4,  8,  8,  16, 1024, 64, 3, true,  0, true ><<<dim3(1024, 1, 4), 256, 0, stream>>>(packed, l1, w1, b1, g1, be1, m1, v1);
  conv_mfma<8,  8,  16, 16, 512,  64, 3, true,  1, true ><<<dim3(256,  1, 4), 256, 0, stream>>>(l1,  l2, w2, b2, g2, be2, m2, v2);
  conv_mfma<16, 16, 32, 16, 256,  32, 5, true,  1, true ><<<dim3(128,  2, 4), 256, 0, stream>>>(l2,  l3, w3, b3, g3, be3, m3, v3);
  conv_mfma<32, 32, 64, 16, 128,  16, 9, false, 1, false><<<dim3(64,   4, 4), 256, 0, stream>>>(l3, outp, w4, b4, g4, be4, m4, v4);
}

// Round 11
// 101.009 us; speedup vs baseline: 1.4932x; 1.0615x over previous
//
#include <hip/hip_runtime.h>
#include <cstdint>
#include <cstddef>

#define HH 1024
#define WW 1024
#define NB 4

typedef _Float16 half8 __attribute__((ext_vector_type(8)));
typedef float f32x4 __attribute__((ext_vector_type(4)));
typedef unsigned long long ull;

// ---------------------------------------------------------------------------
// Fast clear for the 16 MB packed-cell buffer (~5.5 TB/s).
// ---------------------------------------------------------------------------
__global__ __launch_bounds__(256)
void clear_cells(float4* __restrict__ p, int n4) {
  int stride = gridDim.x * blockDim.x;
  float4 z; z.x = 0.f; z.y = 0.f; z.z = 0.f; z.w = 0.f;
  for (int i = blockIdx.x * blockDim.x + threadIdx.x; i < n4; i += stride)
    p[i] = z;
}

// ---------------------------------------------------------------------------
// Scatter: 4 per-cell stats packed in ONE u32 updated by CAS.
//   [31:24] zmax_q8 | [23:16] 255-zmin_q8 | [15:8] iv_q8 | [7:0] cnt (sat 255)
// All-zero word == empty cell. Optimistic first CAS (~90% one-shot).
// R10 lesson: scatter is atomic-OP-RATE bound (~24 G CAS/s), not line-bound —
// u64->u32 cells moved nothing. Leave as-is.
// ---------------------------------------------------------------------------
__device__ __forceinline__ unsigned merge_cell(unsigned a, unsigned zq,
                                               unsigned zn, unsigned iq) {
  unsigned cnt = a & 0xFFu;
  unsigned civ = (a >> 8) & 0xFFu;
  unsigned czn = (a >> 16) & 0xFFu;
  unsigned czx = a >> 24;
  cnt = (cnt < 255u) ? cnt + 1u : cnt;
  civ = civ > iq ? civ : iq;
  czn = czn > zn ? czn : zn;
  czx = czx > zq ? czx : zq;
  return cnt | (civ << 8) | (czn << 16) | (czx << 24);
}

__global__ __launch_bounds__(256)
void scatter_points_packed(const float* __restrict__ pts, int n,
                           unsigned* __restrict__ cell) {
  const float xs   = (float)(1024.0 / 69.12);
  const float ys   = (float)(1024.0 / (39.68 + 39.68));
  const float yoff = 39.68f;
  int i = blockIdx.x * blockDim.x + threadIdx.x;
  if (i >= n) return;
  float b  = pts[(size_t)i * 5 + 0];
  float x  = pts[(size_t)i * 5 + 1];
  float y  = pts[(size_t)i * 5 + 2];
  float z  = pts[(size_t)i * 5 + 3];
  float it = pts[(size_t)i * 5 + 4];
  int xp = (int)(x * xs);                 // trunc toward zero == astype(int32)
  int yp = (int)((y + yoff) * ys);
  if (xp < 0 || xp >= WW || yp < 0 || yp >= HH) return;
  int lin = ((int)b * HH + yp) * WW + xp;

  float zc = fminf(fmaxf(z, -3.f), 1.f);
  unsigned zq = (unsigned)(int)((zc + 3.f) * (255.f / 4.f) + 0.5f);
  if (zq > 255u) zq = 255u;
  float ic = fminf(fmaxf(it, 0.f), 1.f);
  unsigned iq = (unsigned)(int)(ic * 255.f + 0.5f);
  if (iq > 255u) iq = 255u;
  unsigned zn = 255u - zq;

  unsigned g = atomicCAS(&cell[lin], 0u, merge_cell(0u, zq, zn, iq));
  while (g != 0u) {
    unsigned r = atomicCAS(&cell[lin], g, merge_cell(g, zq, zn, iq));
    if (r == g) break;
    g = r;
  }
}

// ---------------------------------------------------------------------------
// Implicit-GEMM conv3x3 + bias + BN + ReLU (+2x2 maxpool) via MFMA f16.
// 512 threads / 8 waves per block; 32 y-rows x PXT x-cols, co group
// [cobase, cobase+COp). Wave w owns y-rows w*4..w*4+3.
// INMODE 0: packed-u32 BEV input (CIp=8, 4 real ci + 4 zero pad).
// INMODE 1: channels-last f16 [b][y][x][CI], k = tap*CIp+ci.
// OUTCL: true = channels-last f16 out; false = NCHW f32 (final layer).
// NOTE: LDS A-fragment loads must stay 16B-aligned (cell stride multiple of
// 8 f16) or ds_read_b128 scalarizes — R8's CIp=4 packing cost 3x (72us).
// ---------------------------------------------------------------------------
template<int CI, int CIp, int COT, int COp, int HWI, int PXT, int KS,
         bool POOL, int INMODE, bool OUTCL>
__global__ __launch_bounds__(512)
void conv_mfma(const void* __restrict__ in, void* __restrict__ outv,
               const float* __restrict__ wgt, const float* __restrict__ bias,
               const float* __restrict__ gam, const float* __restrict__ bet,
               const float* __restrict__ mean, const float* __restrict__ var) {
  constexpr int PYT  = 32;
  constexpr int NTHR = 512;
  constexpr int NT   = COp / 16;
  constexpr int XH   = PXT / 16;
  constexpr int NCOL = PXT + 2;
  constexpr int NCELL = (PYT + 2) * NCOL;
  constexpr int WROW = KS * 32 + 8;
  constexpr int INE  = NCELL * CIp;
  constexpr int L2C  = (CIp == 8) ? 3 : ((CIp == 16) ? 4 : 5);
  constexpr int KTOT = 9 * CIp;
  constexpr int COR  = (COT < COp) ? COT : COp;
  constexpr int PXH  = PXT / 2;
  constexpr int OCS  = 136;              // no-pool out-stage stride (floats)
  static_assert(CIp % 8 == 0 && COp % 16 == 0, "");
  static_assert(!OUTCL || (POOL && COT % 8 == 0), "");
  static_assert(!POOL || 16 * PXH * COp * 2 <= INE * 2, "out overlay fits");
  static_assert(POOL || COp * OCS * 4 <= INE * 2, "out overlay fits");

  __shared__ __align__(16) char s_raw[INE * 2 + COp * WROW * 2 + COp * 8];
  _Float16* s_in = (_Float16*)s_raw;
  _Float16* s_w  = (_Float16*)(s_raw + INE * 2);
  float* s_scale = (float*)(s_raw + INE * 2 + (size_t)COp * WROW * 2);
  float* s_shift = s_scale + COp;

  const int cobase = blockIdx.y * COp;
  const int b = blockIdx.z;
  constexpr int NPX = HWI / PXT;
  const int pyi = blockIdx.x / NPX;
  const int pxi = blockIdx.x - pyi * NPX;
  const int y0 = pyi * PYT, x0 = pxi * PXT;

  half8 zv;
  #pragma unroll
  for (int q = 0; q < 8; ++q) zv[q] = (_Float16)0.f;

  // ---- stage input patch (one cell per iteration; all ci vectorized)
  if constexpr (INMODE == 0) {
    const unsigned* pin = (const unsigned*)in;
    for (int t = threadIdx.x; t < NCELL; t += NTHR) {
      int col = t % NCOL;
      int row = t / NCOL;
      int gy = y0 - 1 + row, gx = x0 - 1 + col;
      half8 v = zv;                                  // halo: zeros
      if (gy >= 0 && gy < HH && gx >= 0 && gx < WW) {
        unsigned pv = pin[((size_t)b * HH + gy) * WW + gx];
        unsigned cnt = pv & 0xFFu;
        unsigned ivq = (pv >> 8) & 0xFFu;
        unsigned znq = (pv >> 16) & 0xFFu;
        unsigned zxq = pv >> 24;
        float c0, c1, c2, c3;
        if (cnt == 0) { c0 = 0.02f; c1 = 10.f; c2 = -10.f; c3 = 0.f; }
        else {
          c0 = (float)cnt * 0.02f;
          c1 = (float)(255u - znq) * (4.0f / 255.0f) - 3.0f;
          c2 = (float)zxq * (4.0f / 255.0f) - 3.0f;
          c3 = (float)ivq * (1.0f / 255.0f);
        }
        v[0] = (_Float16)c0; v[1] = (_Float16)c1;
        v[2] = (_Float16)c2; v[3] = (_Float16)c3;
      }
      *(half8*)&s_in[(size_t)t * CIp] = v;           // CIp==8, swz==0
    }
  } else {
    const _Float16* fin = (const _Float16*)in;       // [b][y][x][CI]
    for (int t = threadIdx.x; t < NCELL; t += NTHR) {
      int col = t % NCOL;
      int row = t / NCOL;
      int gy = y0 - 1 + row, gx = x0 - 1 + col;
      bool okc = (gy >= 0 && gy < HWI && gx >= 0 && gx < HWI);
      int swz = (CIp == 8) ? 0 : ((CIp == 16) ? ((col >> 2) & 1) : ((col >> 1) & 3));
      #pragma unroll
      for (int c8 = 0; c8 < CIp / 8; ++c8) {
        half8 v = zv;
        if (okc)
          v = *(const half8*)((const _Float16*)fin +
                (((size_t)b * HWI + gy) * HWI + gx) * CI + c8 * 8);
        *(half8*)&s_in[(size_t)t * CIp + ((c8 ^ swz) << 3)] = v;
      }
    }
  }
  // ---- stage weights (this group's co only), reordered [co][tap*CIp+ci]
  for (int t = threadIdx.x; t < COp * KS * 32; t += NTHR) {
    int k   = t % (KS * 32);
    int col = t / (KS * 32);
    int cog = cobase + col;
    float v = 0.f;
    if (k < KTOT && cog < COT) {
      int tap = k / CIp, ci = k % CIp;
      if (ci < CI) v = wgt[((size_t)cog * CI + ci) * 9 + tap];
    }
    s_w[col * WROW + k] = (_Float16)v;
  }
  if (threadIdx.x < COp) {
    int col = threadIdx.x;
    int cog = cobase + col;
    float sc = 0.f, sh = 0.f;
    if (cog < COT) {
      sc = gam[cog] / sqrtf(var[cog] + 1e-5f);
      sh = (bias[cog] - mean[cog]) * sc + bet[cog];
    }
    s_scale[col] = sc; s_shift[col] = sh;
  }
  __syncthreads();

  const int lane = threadIdx.x & 63;
  const int w    = threadIdx.x >> 6;   // wave 0..7, owns y-rows w*4..w*4+3
  const int m    = lane & 15;
  const int hi   = lane >> 4;

  f32x4 acc[4][XH][NT];
  #pragma unroll
  for (int r = 0; r < 4; ++r)
    #pragma unroll
    for (int h = 0; h < XH; ++h)
      #pragma unroll
      for (int n = 0; n < NT; ++n) acc[r][h][n] = 0.f;

  const int y0w = w * 4;
  #pragma unroll
  for (int ks = 0; ks < KS; ++ks) {
    int kc  = ks * 32 + (hi << 3);
    int tap = kc >> L2C;
    if (tap > 8) tap = 8;                 // pad region: real data * zero weight
    int ci  = kc & (CIp - 1);
    int dy  = (tap * 11) >> 5;            // tap/3 for tap in [0,8]
    int dx  = tap - 3 * dy;
    int colA  = m + dx;
    int chunk = ci >> 3;
    int swz = (CIp == 8) ? 0 : ((CIp == 16) ? ((colA >> 2) & 1) : ((colA >> 1) & 3));
    int aoff = ((y0w + dy) * NCOL + colA) * CIp + ((chunk ^ swz) << 3);
    const int boff = m * WROW + ks * 32 + (hi << 3);
    half8 bfr[NT];
    #pragma unroll
    for (int n = 0; n < NT; ++n)
      bfr[n] = *(const half8*)&s_w[boff + n * 16 * WROW];
    #pragma unroll
    for (int r = 0; r < 4; ++r) {
      half8 afr[XH];
      #pragma unroll
      for (int h = 0; h < XH; ++h)
        afr[h] = *(const half8*)&s_in[aoff + r * NCOL * CIp + h * 16 * CIp];
      #pragma unroll
      for (int h = 0; h < XH; ++h)
        #pragma unroll
        for (int n = 0; n < NT; ++n)
          acc[r][h][n] = __builtin_amdgcn_mfma_f32_16x16x32_f16(
              afr[h], bfr[n], acc[r][h][n], 0, 0, 0);
    }
  }

  __syncthreads();                       // all LDS reads done; overlay s_in

  if constexpr (POOL) {
    // lane holds conv x = hi*4+q at y-row r; pool x-pairs in-lane, y-pairs
    // across r. Pooled yp = w*2+rp (0..15), xp = h*8+hi*2+{0,1}.
    _Float16* s_o = (_Float16*)s_raw;    // [yp][xp][COp] f16
    #pragma unroll
    for (int n = 0; n < NT; ++n) {
      int col = n * 16 + m;
      float sc = s_scale[col], sh = s_shift[col];
      #pragma unroll
      for (int rp = 0; rp < 2; ++rp) {
        #pragma unroll
        for (int h = 0; h < XH; ++h) {
          f32x4 p0 = acc[rp * 2][h][n];
          f32x4 p1 = acc[rp * 2 + 1][h][n];
          float v0 = fmaxf(fmaxf(p0[0], p0[1]), fmaxf(p1[0], p1[1]));
          float v1 = fmaxf(fmaxf(p0[2], p0[3]), fmaxf(p1[2], p1[3]));
          v0 = fmaxf(v0 * sc + sh, 0.f);
          v1 = fmaxf(v1 * sc + sh, 0.f);
          int yp = w * 2 + rp;
          int xp = h * 8 + hi * 2;
          s_o[(yp * PXH + xp) * COp + col]     = (_Float16)v0;
          s_o[(yp * PXH + xp + 1) * COp + col] = (_Float16)v1;
        }
      }
    }
    __syncthreads();
    constexpr int HWO = HWI / 2;
    constexpr int NCHG = (COR + 7) / 8;  // 8-chunks this group writes
    _Float16* og = (_Float16*)outv;      // [b][HWO][HWO][COT]
    for (int t = threadIdx.x; t < 16 * PXH * NCHG; t += NTHR) {
      int c8  = t % NCHG;
      int rem = t / NCHG;
      int xp  = rem % PXH;
      int yp  = rem / PXH;
      half8 v = *(const half8*)&s_o[(yp * PXH + xp) * COp + c8 * 8];
      *(half8*)&og[(((size_t)b * HWO + (y0 / 2 + yp)) * HWO + (x0 / 2 + xp)) * COT
                   + cobase + c8 * 8] = v;
    }
  } else {
    // final layer: NCHW f32 out; 4 rounds staging one y-row per wave
    float* s_out = (float*)s_raw;
    float* og = (float*)outv;
    #pragma unroll
    for (int r = 0; r < 4; ++r) {
      if (r) __syncthreads();
      #pragma unroll
      for (int n = 0; n < NT; ++n) {
        int col = n * 16 + m;
        float sc = s_scale[col], sh = s_shift[col];
        f32x4 p = acc[r][0][n];
        #pragma unroll
        for (int q = 0; q < 4; ++q) {
          float v = fmaxf(p[q] * sc + sh, 0.f);
          s_out[col * OCS + w * 16 + hi * 4 + q] = v;
        }
      }
      __syncthreads();
      for (int t = threadIdx.x; t < COR * 8 * 16; t += NTHR) {
        int xp = t & 15, ws3 = (t >> 4) & 7, col = t >> 7;
        og[(((size_t)b * COT + cobase + col) * HWI + (y0 + ws3 * 4 + r)) * HWI + (x0 + xp)]
          = s_out[col * OCS + ws3 * 16 + xp];
      }
    }
  }
}

extern "C" void kernel_launch(void* const* d_in, const int* in_sizes, int n_in,
                              void* d_out, int out_size, void* d_ws, size_t ws_size,
                              hipStream_t stream) {
  const float* pts = (const float*)d_in[0];
  const int npts = in_sizes[0] / 5;

  const float* w1  = (const float*)d_in[2];
  const float* b1  = (const float*)d_in[3];
  const float* g1  = (const float*)d_in[4];
  const float* be1 = (const float*)d_in[5];
  const float* m1  = (const float*)d_in[6];
  const float* v1  = (const float*)d_in[7];
  const float* w2  = (const float*)d_in[8];
  const float* b2  = (const float*)d_in[9];
  const float* g2  = (const float*)d_in[10];
  const float* be2 = (const float*)d_in[11];
  const float* m2  = (const float*)d_in[12];
  const float* v2  = (const float*)d_in[13];
  const float* w3  = (const float*)d_in[14];
  const float* b3  = (const float*)d_in[15];
  const float* g3  = (const float*)d_in[16];
  const float* be3 = (const float*)d_in[17];
  const float* m3  = (const float*)d_in[18];
  const float* v3  = (const float*)d_in[19];
  const float* w4  = (const float*)d_in[20];
  const float* b4  = (const float*)d_in[21];
  const float* g4  = (const float*)d_in[22];
  const float* be4 = (const float*)d_in[23];
  const float* m4  = (const float*)d_in[24];
  const float* v4  = (const float*)d_in[25];

  char* ws = (char*)d_ws;
  // Workspace (bytes):
  //   packed cells [0, 16M): u32 per cell
  //   l1 [32M, 48M):  f16 CL (4,512,512,8)
  //   l2 [48M, 56.4M): f16 CL (4,256,256,16)
  //   l3 [56.4M, 60.6M): f16 CL (4,128,128,32)
  unsigned* packed = (unsigned*)ws;
  void* l1 = (void*)(ws + 33554432);
  void* l2 = (void*)(ws + 50331648);
  void* l3 = (void*)(ws + 58720256);
  void* outp = d_out;

  clear_cells<<<2048, 256, 0, stream>>>((float4*)packed, (int)((size_t)NB * HH * WW * 4 / 16));
  scatter_points_packed<<<(npts + 255) / 256, 256, 0, stream>>>(pts, npts, packed);

  // <CI, CIp, COT, COp, HWI, PXT, KS, POOL, INMODE, OUTCL>, 512-thread blocks
  conv_mfma<4,  8,  8,  16, 1024, 64, 3, true,  0, true ><<<dim3(512, 1, 4), 512, 0, stream>>>(packed, l1, w1, b1, g1, be1, m1, v1);
  conv_mfma<8,  8,  16, 16, 512,  64, 3, true,  1, true ><<<dim3(128, 1, 4), 512, 0, stream>>>(l1,  l2, w2, b2, g2, be2, m2, v2);
  conv_mfma<16, 16, 32, 16, 256,  32, 5, true,  1, true ><<<dim3(64,  2, 4), 512, 0, stream>>>(l2,  l3, w3, b3, g3, be3, m3, v3);
  conv_mfma<32, 32, 64, 16, 128,  16, 9, false, 1, false><<<dim3(32,  4, 4), 512, 0, stream>>>(l3, outp, w4, b4, g4, be4, m4, v4);
}

// Round 12
// 95.375 us; speedup vs baseline: 1.5814x; 1.0591x over previous
//
#include <hip/hip_runtime.h>
#include <cstdint>
#include <cstddef>

#define HH 1024
#define WW 1024
#define NB 4

typedef _Float16 half8 __attribute__((ext_vector_type(8)));
typedef _Float16 half4 __attribute__((ext_vector_type(4)));
typedef float f32x4 __attribute__((ext_vector_type(4)));
typedef unsigned long long ull;

// ---------------------------------------------------------------------------
// Fast clear for the 16 MB packed-cell buffer (~5.5 TB/s).
// ---------------------------------------------------------------------------
__global__ __launch_bounds__(256)
void clear_cells(float4* __restrict__ p, int n4) {
  int stride = gridDim.x * blockDim.x;
  float4 z; z.x = 0.f; z.y = 0.f; z.z = 0.f; z.w = 0.f;
  for (int i = blockIdx.x * blockDim.x + threadIdx.x; i < n4; i += stride)
    p[i] = z;
}

// ---------------------------------------------------------------------------
// Scatter: 4 per-cell stats packed in ONE u32 updated by CAS.
//   [31:24] zmax_q8 | [23:16] 255-zmin_q8 | [15:8] iv_q8 | [7:0] cnt (sat 255)
// All-zero word == empty cell. Optimistic first CAS (~90% one-shot).
// R10 lesson: scatter is atomic-OP-RATE bound (~24 G CAS/s), not line-bound.
// ---------------------------------------------------------------------------
__device__ __forceinline__ unsigned merge_cell(unsigned a, unsigned zq,
                                               unsigned zn, unsigned iq) {
  unsigned cnt = a & 0xFFu;
  unsigned civ = (a >> 8) & 0xFFu;
  unsigned czn = (a >> 16) & 0xFFu;
  unsigned czx = a >> 24;
  cnt = (cnt < 255u) ? cnt + 1u : cnt;
  civ = civ > iq ? civ : iq;
  czn = czn > zn ? czn : zn;
  czx = czx > zq ? czx : zq;
  return cnt | (civ << 8) | (czn << 16) | (czx << 24);
}

__global__ __launch_bounds__(256)
void scatter_points_packed(const float* __restrict__ pts, int n,
                           unsigned* __restrict__ cell) {
  const float xs   = (float)(1024.0 / 69.12);
  const float ys   = (float)(1024.0 / (39.68 + 39.68));
  const float yoff = 39.68f;
  int i = blockIdx.x * blockDim.x + threadIdx.x;
  if (i >= n) return;
  float b  = pts[(size_t)i * 5 + 0];
  float x  = pts[(size_t)i * 5 + 1];
  float y  = pts[(size_t)i * 5 + 2];
  float z  = pts[(size_t)i * 5 + 3];
  float it = pts[(size_t)i * 5 + 4];
  int xp = (int)(x * xs);                 // trunc toward zero == astype(int32)
  int yp = (int)((y + yoff) * ys);
  if (xp < 0 || xp >= WW || yp < 0 || yp >= HH) return;
  int lin = ((int)b * HH + yp) * WW + xp;

  float zc = fminf(fmaxf(z, -3.f), 1.f);
  unsigned zq = (unsigned)(int)((zc + 3.f) * (255.f / 4.f) + 0.5f);
  if (zq > 255u) zq = 255u;
  float ic = fminf(fmaxf(it, 0.f), 1.f);
  unsigned iq = (unsigned)(int)(ic * 255.f + 0.5f);
  if (iq > 255u) iq = 255u;
  unsigned zn = 255u - zq;

  unsigned g = atomicCAS(&cell[lin], 0u, merge_cell(0u, zq, zn, iq));
  while (g != 0u) {
    unsigned r = atomicCAS(&cell[lin], g, merge_cell(g, zq, zn, iq));
    if (r == g) break;
    g = r;
  }
}

// ---------------------------------------------------------------------------
// Implicit-GEMM conv3x3 + bias + BN + ReLU (+2x2 maxpool) via MFMA f16.
// 512 threads / 8 waves per block; 32 y-rows x PXT x-cols, co group
// [cobase, cobase+COp). Wave w owns y-rows w*4..w*4+3.
// INMODE 0 (conv1, packed-u32 BEV, CI=4): tap-PAIR K-packing, KS=2 (K=64).
//   LDS slot [row][col] (8 f16, 16B): low = cell(col) ci0-3, high =
//   cell(col+1) ci0-3 (duplicated). k-group p: p<6 covers x-adjacent tap
//   pair (tA, tA+1), tA = p+((p+1)>>1); odd p & p>=6 high halves get zero
//   weights (finite data x 0). Fixes R8's 8B-alignment scalarization while
//   cutting KS 3->2.
// INMODE 1: channels-last f16 [b][y][x][CI], k = tap*CIp+ci.
// OUTCL: true = channels-last f16 out; false = NCHW f32 (final layer).
// NOTE: LDS A-fragment loads must stay 16B-aligned (slot stride multiple of
// 8 f16) or ds_read_b128 scalarizes — R8's CIp=4 packing cost 3x (72us).
// ---------------------------------------------------------------------------
template<int CI, int CIp, int COT, int COp, int HWI, int PXT, int KS,
         bool POOL, int INMODE, bool OUTCL>
__global__ __launch_bounds__(512)
void conv_mfma(const void* __restrict__ in, void* __restrict__ outv,
               const float* __restrict__ wgt, const float* __restrict__ bias,
               const float* __restrict__ gam, const float* __restrict__ bet,
               const float* __restrict__ mean, const float* __restrict__ var) {
  constexpr int PYT  = 32;
  constexpr int NTHR = 512;
  constexpr int NT   = COp / 16;
  constexpr int XH   = PXT / 16;
  constexpr int NCOL = PXT + 2;
  constexpr int NCELL = (PYT + 2) * NCOL;
  constexpr int WROW = KS * 32 + 8;
  constexpr int INE  = NCELL * CIp;
  constexpr int L2C  = (CIp == 8) ? 3 : ((CIp == 16) ? 4 : 5);
  constexpr int KTOT = 9 * CIp;
  constexpr int COR  = (COT < COp) ? COT : COp;
  constexpr int PXH  = PXT / 2;
  constexpr int OCS  = 136;              // no-pool out-stage stride (floats)
  static_assert(CIp % 8 == 0 && COp % 16 == 0, "");
  static_assert(INMODE != 0 || (CI == 4 && CIp == 8 && KS == 2), "");
  static_assert(!OUTCL || (POOL && COT % 8 == 0), "");
  static_assert(!POOL || 16 * PXH * COp * 2 <= INE * 2, "out overlay fits");
  static_assert(POOL || COp * OCS * 4 <= INE * 2, "out overlay fits");

  __shared__ __align__(16) char s_raw[INE * 2 + COp * WROW * 2 + COp * 8];
  _Float16* s_in = (_Float16*)s_raw;
  _Float16* s_w  = (_Float16*)(s_raw + INE * 2);
  float* s_scale = (float*)(s_raw + INE * 2 + (size_t)COp * WROW * 2);
  float* s_shift = s_scale + COp;

  const int cobase = blockIdx.y * COp;
  const int b = blockIdx.z;
  constexpr int NPX = HWI / PXT;
  const int pyi = blockIdx.x / NPX;
  const int pxi = blockIdx.x - pyi * NPX;
  const int y0 = pyi * PYT, x0 = pxi * PXT;

  half8 zv;
  #pragma unroll
  for (int q = 0; q < 8; ++q) zv[q] = (_Float16)0.f;

  // ---- stage input patch
  if constexpr (INMODE == 0) {
    const unsigned* pin = (const unsigned*)in;
    for (int t = threadIdx.x; t < NCELL; t += NTHR) {
      int col = t % NCOL;
      int row = t / NCOL;
      int gy = y0 - 1 + row, gx = x0 - 1 + col;
      half4 v;
      v[0] = (_Float16)0.f; v[1] = (_Float16)0.f;
      v[2] = (_Float16)0.f; v[3] = (_Float16)0.f;
      if (gy >= 0 && gy < HH && gx >= 0 && gx < WW) {
        unsigned pv = pin[((size_t)b * HH + gy) * WW + gx];
        unsigned cnt = pv & 0xFFu;
        unsigned ivq = (pv >> 8) & 0xFFu;
        unsigned znq = (pv >> 16) & 0xFFu;
        unsigned zxq = pv >> 24;
        float c0, c1, c2, c3;
        if (cnt == 0) { c0 = 0.02f; c1 = 10.f; c2 = -10.f; c3 = 0.f; }
        else {
          c0 = (float)cnt * 0.02f;
          c1 = (float)(255u - znq) * (4.0f / 255.0f) - 3.0f;
          c2 = (float)zxq * (4.0f / 255.0f) - 3.0f;
          c3 = (float)ivq * (1.0f / 255.0f);
        }
        v[0] = (_Float16)c0; v[1] = (_Float16)c1;
        v[2] = (_Float16)c2; v[3] = (_Float16)c3;
      }
      // own slot low half (16B-aligned base)
      *(half4*)&s_in[(size_t)t * 8] = v;
      // duplicate into left neighbor's high half
      if (col > 0)
        *(half4*)&s_in[(size_t)(t - 1) * 8 + 4] = v;
      // rightmost slot's high half has no producer -> zero it (finite)
      if (col == NCOL - 1) {
        half4 z4;
        z4[0] = (_Float16)0.f; z4[1] = (_Float16)0.f;
        z4[2] = (_Float16)0.f; z4[3] = (_Float16)0.f;
        *(half4*)&s_in[(size_t)t * 8 + 4] = z4;
      }
    }
  } else {
    const _Float16* fin = (const _Float16*)in;       // [b][y][x][CI]
    for (int t = threadIdx.x; t < NCELL; t += NTHR) {
      int col = t % NCOL;
      int row = t / NCOL;
      int gy = y0 - 1 + row, gx = x0 - 1 + col;
      bool okc = (gy >= 0 && gy < HWI && gx >= 0 && gx < HWI);
      int swz = (CIp == 8) ? 0 : ((CIp == 16) ? ((col >> 2) & 1) : ((col >> 1) & 3));
      #pragma unroll
      for (int c8 = 0; c8 < CIp / 8; ++c8) {
        half8 v = zv;
        if (okc)
          v = *(const half8*)((const _Float16*)fin +
                (((size_t)b * HWI + gy) * HWI + gx) * CI + c8 * 8);
        *(half8*)&s_in[(size_t)t * CIp + ((c8 ^ swz) << 3)] = v;
      }
    }
  }
  // ---- stage weights
  if constexpr (INMODE == 0) {
    // k = p*8+j: p<6 -> tap pair (tA, tA+1), tA = p+((p+1)>>1).
    // j<4: w[co][j][tA]; j>=4: w[co][j-4][tA+1] if p even, else 0. p>=6: 0.
    for (int t = threadIdx.x; t < COp * KS * 32; t += NTHR) {
      int k   = t % (KS * 32);
      int col = t / (KS * 32);
      int cog = cobase + col;
      int p = k >> 3, j = k & 7;
      float v = 0.f;
      if (p < 6 && cog < COT) {
        int tA = p + ((p + 1) >> 1);
        int ci = j & 3;
        if (j < 4) v = wgt[((size_t)cog * CI + ci) * 9 + tA];
        else if ((p & 1) == 0) v = wgt[((size_t)cog * CI + ci) * 9 + tA + 1];
      }
      s_w[col * WROW + k] = (_Float16)v;
    }
  } else {
    for (int t = threadIdx.x; t < COp * KS * 32; t += NTHR) {
      int k   = t % (KS * 32);
      int col = t / (KS * 32);
      int cog = cobase + col;
      float v = 0.f;
      if (k < KTOT && cog < COT) {
        int tap = k / CIp, ci = k % CIp;
        if (ci < CI) v = wgt[((size_t)cog * CI + ci) * 9 + tap];
      }
      s_w[col * WROW + k] = (_Float16)v;
    }
  }
  if (threadIdx.x < COp) {
    int col = threadIdx.x;
    int cog = cobase + col;
    float sc = 0.f, sh = 0.f;
    if (cog < COT) {
      sc = gam[cog] / sqrtf(var[cog] + 1e-5f);
      sh = (bias[cog] - mean[cog]) * sc + bet[cog];
    }
    s_scale[col] = sc; s_shift[col] = sh;
  }
  __syncthreads();

  const int lane = threadIdx.x & 63;
  const int w    = threadIdx.x >> 6;   // wave 0..7, owns y-rows w*4..w*4+3
  const int m    = lane & 15;
  const int hi   = lane >> 4;

  f32x4 acc[4][XH][NT];
  #pragma unroll
  for (int r = 0; r < 4; ++r)
    #pragma unroll
    for (int h = 0; h < XH; ++h)
      #pragma unroll
      for (int n = 0; n < NT; ++n) acc[r][h][n] = 0.f;

  const int y0w = w * 4;
  #pragma unroll
  for (int ks = 0; ks < KS; ++ks) {
    int aoff;
    if constexpr (INMODE == 0) {
      int p = ks * 4 + hi;
      if (p > 5) p = 5;                   // pad groups: finite data x 0 weight
      int dy  = p >> 1;
      int dxA = (p & 1) << 1;
      aoff = ((y0w + dy) * NCOL + m + dxA) * 8;
    } else {
      int kc  = ks * 32 + (hi << 3);
      int tap = kc >> L2C;
      if (tap > 8) tap = 8;               // pad region: real data * zero weight
      int ci  = kc & (CIp - 1);
      int dy  = (tap * 11) >> 5;          // tap/3 for tap in [0,8]
      int dx  = tap - 3 * dy;
      int colA  = m + dx;
      int chunk = ci >> 3;
      int swz = (CIp == 8) ? 0 : ((CIp == 16) ? ((colA >> 2) & 1) : ((colA >> 1) & 3));
      aoff = ((y0w + dy) * NCOL + colA) * CIp + ((chunk ^ swz) << 3);
    }
    const int boff = m * WROW + ks * 32 + (hi << 3);
    half8 bfr[NT];
    #pragma unroll
    for (int n = 0; n < NT; ++n)
      bfr[n] = *(const half8*)&s_w[boff + n * 16 * WROW];
    #pragma unroll
    for (int r = 0; r < 4; ++r) {
      half8 afr[XH];
      #pragma unroll
      for (int h = 0; h < XH; ++h)
        afr[h] = *(const half8*)&s_in[aoff + r * NCOL * CIp + h * 16 * CIp];
      #pragma unroll
      for (int h = 0; h < XH; ++h)
        #pragma unroll
        for (int n = 0; n < NT; ++n)
          acc[r][h][n] = __builtin_amdgcn_mfma_f32_16x16x32_f16(
              afr[h], bfr[n], acc[r][h][n], 0, 0, 0);
    }
  }

  __syncthreads();                       // all LDS reads done; overlay s_in

  if constexpr (POOL) {
    // lane holds conv x = hi*4+q at y-row r; pool x-pairs in-lane, y-pairs
    // across r. Pooled yp = w*2+rp (0..15), xp = h*8+hi*2+{0,1}.
    _Float16* s_o = (_Float16*)s_raw;    // [yp][xp][COp] f16
    #pragma unroll
    for (int n = 0; n < NT; ++n) {
      int col = n * 16 + m;
      float sc = s_scale[col], sh = s_shift[col];
      #pragma unroll
      for (int rp = 0; rp < 2; ++rp) {
        #pragma unroll
        for (int h = 0; h < XH; ++h) {
          f32x4 p0 = acc[rp * 2][h][n];
          f32x4 p1 = acc[rp * 2 + 1][h][n];
          float v0 = fmaxf(fmaxf(p0[0], p0[1]), fmaxf(p1[0], p1[1]));
          float v1 = fmaxf(fmaxf(p0[2], p0[3]), fmaxf(p1[2], p1[3]));
          v0 = fmaxf(v0 * sc + sh, 0.f);
          v1 = fmaxf(v1 * sc + sh, 0.f);
          int yp = w * 2 + rp;
          int xp = h * 8 + hi * 2;
          s_o[(yp * PXH + xp) * COp + col]     = (_Float16)v0;
          s_o[(yp * PXH + xp + 1) * COp + col] = (_Float16)v1;
        }
      }
    }
    __syncthreads();
    constexpr int HWO = HWI / 2;
    constexpr int NCHG = (COR + 7) / 8;  // 8-chunks this group writes
    _Float16* og = (_Float16*)outv;      // [b][HWO][HWO][COT]
    for (int t = threadIdx.x; t < 16 * PXH * NCHG; t += NTHR) {
      int c8  = t % NCHG;
      int rem = t / NCHG;
      int xp  = rem % PXH;
      int yp  = rem / PXH;
      half8 v = *(const half8*)&s_o[(yp * PXH + xp) * COp + c8 * 8];
      *(half8*)&og[(((size_t)b * HWO + (y0 / 2 + yp)) * HWO + (x0 / 2 + xp)) * COT
                   + cobase + c8 * 8] = v;
    }
  } else {
    // final layer: NCHW f32 out; 4 rounds staging one y-row per wave
    float* s_out = (float*)s_raw;
    float* og = (float*)outv;
    #pragma unroll
    for (int r = 0; r < 4; ++r) {
      if (r) __syncthreads();
      #pragma unroll
      for (int n = 0; n < NT; ++n) {
        int col = n * 16 + m;
        float sc = s_scale[col], sh = s_shift[col];
        f32x4 p = acc[r][0][n];
        #pragma unroll
        for (int q = 0; q < 4; ++q) {
          float v = fmaxf(p[q] * sc + sh, 0.f);
          s_out[col * OCS + w * 16 + hi * 4 + q] = v;
        }
      }
      __syncthreads();
      for (int t = threadIdx.x; t < COR * 8 * 16; t += NTHR) {
        int xp = t & 15, ws3 = (t >> 4) & 7, col = t >> 7;
        og[(((size_t)b * COT + cobase + col) * HWI + (y0 + ws3 * 4 + r)) * HWI + (x0 + xp)]
          = s_out[col * OCS + ws3 * 16 + xp];
      }
    }
  }
}

extern "C" void kernel_launch(void* const* d_in, const int* in_sizes, int n_in,
                              void* d_out, int out_size, void* d_ws, size_t ws_size,
                              hipStream_t stream) {
  const float* pts = (const float*)d_in[0];
  const int npts = in_sizes[0] / 5;

  const float* w1  = (const float*)d_in[2];
  const float* b1  = (const float*)d_in[3];
  const float* g1  = (const float*)d_in[4];
  const float* be1 = (const float*)d_in[5];
  const float* m1  = (const float*)d_in[6];
  const float* v1  = (const float*)d_in[7];
  const float* w2  = (const float*)d_in[8];
  const float* b2  = (const float*)d_in[9];
  const float* g2  = (const float*)d_in[10];
  const float* be2 = (const float*)d_in[11];
  const float* m2  = (const float*)d_in[12];
  const float* v2  = (const float*)d_in[13];
  const float* w3  = (const float*)d_in[14];
  const float* b3  = (const float*)d_in[15];
  const float* g3  = (const float*)d_in[16];
  const float* be3 = (const float*)d_in[17];
  const float* m3  = (const float*)d_in[18];
  const float* v3  = (const float*)d_in[19];
  const float* w4  = (const float*)d_in[20];
  const float* b4  = (const float*)d_in[21];
  const float* g4  = (const float*)d_in[22];
  const float* be4 = (const float*)d_in[23];
  const float* m4  = (const float*)d_in[24];
  const float* v4  = (const float*)d_in[25];

  char* ws = (char*)d_ws;
  // Workspace (bytes):
  //   packed cells [0, 16M): u32 per cell
  //   l1 [32M, 48M):  f16 CL (4,512,512,8)
  //   l2 [48M, 56.4M): f16 CL (4,256,256,16)
  //   l3 [56.4M, 60.6M): f16 CL (4,128,128,32)
  unsigned* packed = (unsigned*)ws;
  void* l1 = (void*)(ws + 33554432);
  void* l2 = (void*)(ws + 50331648);
  void* l3 = (void*)(ws + 58720256);
  void* outp = d_out;

  clear_cells<<<2048, 256, 0, stream>>>((float4*)packed, (int)((size_t)NB * HH * WW * 4 / 16));
  scatter_points_packed<<<(npts + 255) / 256, 256, 0, stream>>>(pts, npts, packed);

  // <CI, CIp, COT, COp, HWI, PXT, KS, POOL, INMODE, OUTCL>, 512-thread blocks
  conv_mfma<4,  8,  8,  16, 1024, 64, 2, true,  0, true ><<<dim3(512, 1, 4), 512, 0, stream>>>(packed, l1, w1, b1, g1, be1, m1, v1);
  conv_mfma<8,  8,  16, 16, 512,  64, 3, true,  1, true ><<<dim3(128, 1, 4), 512, 0, stream>>>(l1,  l2, w2, b2, g2, be2, m2, v2);
  conv_mfma<16, 16, 32, 16, 256,  32, 5, true,  1, true ><<<dim3(64,  2, 4), 512, 0, stream>>>(l2,  l3, w3, b3, g3, be3, m3, v3);
  conv_mfma<32, 32, 64, 16, 128,  16, 9, false, 1, false><<<dim3(32,  4, 4), 512, 0, stream>>>(l3, outp, w4, b4, g4, be4, m4, v4);
}

// Round 13
// 93.869 us; speedup vs baseline: 1.6067x; 1.0160x over previous
//
#include <hip/hip_runtime.h>
#include <cstdint>
#include <cstddef>

#define HH 1024
#define WW 1024
#define NB 4

typedef _Float16 half8 __attribute__((ext_vector_type(8)));
typedef _Float16 half4 __attribute__((ext_vector_type(4)));
typedef float f32x4 __attribute__((ext_vector_type(4)));
typedef unsigned long long ull;

// ---------------------------------------------------------------------------
// Fast clear for the 16 MB packed-cell buffer (~5.5 TB/s).
// ---------------------------------------------------------------------------
__global__ __launch_bounds__(256)
void clear_cells(float4* __restrict__ p, int n4) {
  int stride = gridDim.x * blockDim.x;
  float4 z; z.x = 0.f; z.y = 0.f; z.z = 0.f; z.w = 0.f;
  for (int i = blockIdx.x * blockDim.x + threadIdx.x; i < n4; i += stride)
    p[i] = z;
}

// ---------------------------------------------------------------------------
// Scatter: 4 per-cell stats packed in ONE u32 updated by CAS.
//   [31:24] zmax_q8 | [23:16] 255-zmin_q8 | [15:8] iv_q8 | [7:0] cnt (sat 255)
// All-zero word == empty cell. Optimistic first CAS (~90% one-shot).
// R10 lesson: scatter is atomic-OP-RATE bound (~24 G CAS/s), not line-bound.
// ---------------------------------------------------------------------------
__device__ __forceinline__ unsigned merge_cell(unsigned a, unsigned zq,
                                               unsigned zn, unsigned iq) {
  unsigned cnt = a & 0xFFu;
  unsigned civ = (a >> 8) & 0xFFu;
  unsigned czn = (a >> 16) & 0xFFu;
  unsigned czx = a >> 24;
  cnt = (cnt < 255u) ? cnt + 1u : cnt;
  civ = civ > iq ? civ : iq;
  czn = czn > zn ? czn : zn;
  czx = czx > zq ? czx : zq;
  return cnt | (civ << 8) | (czn << 16) | (czx << 24);
}

__global__ __launch_bounds__(256)
void scatter_points_packed(const float* __restrict__ pts, int n,
                           unsigned* __restrict__ cell) {
  const float xs   = (float)(1024.0 / 69.12);
  const float ys   = (float)(1024.0 / (39.68 + 39.68));
  const float yoff = 39.68f;
  int i = blockIdx.x * blockDim.x + threadIdx.x;
  if (i >= n) return;
  float b  = pts[(size_t)i * 5 + 0];
  float x  = pts[(size_t)i * 5 + 1];
  float y  = pts[(size_t)i * 5 + 2];
  float z  = pts[(size_t)i * 5 + 3];
  float it = pts[(size_t)i * 5 + 4];
  int xp = (int)(x * xs);                 // trunc toward zero == astype(int32)
  int yp = (int)((y + yoff) * ys);
  if (xp < 0 || xp >= WW || yp < 0 || yp >= HH) return;
  int lin = ((int)b * HH + yp) * WW + xp;

  float zc = fminf(fmaxf(z, -3.f), 1.f);
  unsigned zq = (unsigned)(int)((zc + 3.f) * (255.f / 4.f) + 0.5f);
  if (zq > 255u) zq = 255u;
  float ic = fminf(fmaxf(it, 0.f), 1.f);
  unsigned iq = (unsigned)(int)(ic * 255.f + 0.5f);
  if (iq > 255u) iq = 255u;
  unsigned zn = 255u - zq;

  unsigned g = atomicCAS(&cell[lin], 0u, merge_cell(0u, zq, zn, iq));
  while (g != 0u) {
    unsigned r = atomicCAS(&cell[lin], g, merge_cell(g, zq, zn, iq));
    if (r == g) break;
    g = r;
  }
}

// ---------------------------------------------------------------------------
// Implicit-GEMM conv3x3 + bias + BN + ReLU (+2x2 maxpool) via MFMA f16.
// 512 threads / 8 waves per block; 32 y-rows x PXT x-cols, co group
// [cobase, cobase+COp). Wave w owns y-rows w*4..w*4+3.
// INMODE 0 (conv1, packed-u32 BEV, CI=4, CO=8): dual-x N-packing.
//   LDS slot s of a row = cells (2s, 2s+1), 4 ci each (16B, b128-aligned).
//   K=64 (KS=2): k-group p<6 -> dy=p>>1, slot m+(p&1): low j = cell dx
//   {0 or 2}, high j = cell dx {1 or 3} relative to x_even = x0+h*32+2m.
//   B cols 0-7 = co with normal taps -> out(x_even); cols 8-15 = co with
//   x-shifted taps (cell dx 1,2,3 -> w dx 0,1,2) -> out(x_even+1). M covers
//   x at stride 2 => MFMA count and A-reads HALVED vs R12. Epilogue x-pools
//   (even,odd) across lanes n<->n+8 via shfl_xor before BN (scale>0).
// INMODE 1: channels-last f16 [b][y][x][CI], k = tap*CIp+ci.
// OUTCL: true = channels-last f16 out; false = NCHW f32 (final layer).
// NOTE: LDS A-fragment loads must stay 16B-aligned (slot stride multiple of
// 8 f16) or ds_read_b128 scalarizes — R8's CIp=4 packing cost 3x (72us).
// ---------------------------------------------------------------------------
template<int CI, int CIp, int COT, int COp, int HWI, int PXT, int KS,
         bool POOL, int INMODE, bool OUTCL>
__global__ __launch_bounds__(512)
void conv_mfma(const void* __restrict__ in, void* __restrict__ outv,
               const float* __restrict__ wgt, const float* __restrict__ bias,
               const float* __restrict__ gam, const float* __restrict__ bet,
               const float* __restrict__ mean, const float* __restrict__ var) {
  constexpr int PYT  = 32;
  constexpr int NTHR = 512;
  constexpr int NT   = COp / 16;
  constexpr int XH   = (INMODE == 0) ? (PXT / 32) : (PXT / 16);
  constexpr int NCOL = PXT + 2;
  constexpr int NSLOT = (INMODE == 0) ? ((NCOL + 1) / 2) : NCOL;
  constexpr int NCELL = (PYT + 2) * NCOL;
  constexpr int WROW = KS * 32 + 8;
  constexpr int INE  = (PYT + 2) * NSLOT * CIp;
  constexpr int L2C  = (CIp == 8) ? 3 : ((CIp == 16) ? 4 : 5);
  constexpr int KTOT = 9 * CIp;
  constexpr int COR  = (COT < COp) ? COT : COp;
  constexpr int PXH  = PXT / 2;
  constexpr int OCS  = 136;              // no-pool out-stage stride (floats)
  static_assert(CIp % 8 == 0 && COp % 16 == 0, "");
  static_assert(INMODE != 0 || (CI == 4 && CIp == 8 && KS == 2 && COT == 8 && COp == 16), "");
  static_assert(!OUTCL || (POOL && COT % 8 == 0), "");
  static_assert(!POOL || 16 * PXH * COp * 2 <= INE * 2, "out overlay fits");
  static_assert(POOL || COp * OCS * 4 <= INE * 2, "out overlay fits");

  __shared__ __align__(16) char s_raw[INE * 2 + COp * WROW * 2 + COp * 8];
  _Float16* s_in = (_Float16*)s_raw;
  _Float16* s_w  = (_Float16*)(s_raw + INE * 2);
  float* s_scale = (float*)(s_raw + INE * 2 + (size_t)COp * WROW * 2);
  float* s_shift = s_scale + COp;

  const int cobase = blockIdx.y * COp;
  const int b = blockIdx.z;
  constexpr int NPX = HWI / PXT;
  const int pyi = blockIdx.x / NPX;
  const int pxi = blockIdx.x - pyi * NPX;
  const int y0 = pyi * PYT, x0 = pxi * PXT;

  half8 zv;
  #pragma unroll
  for (int q = 0; q < 8; ++q) zv[q] = (_Float16)0.f;

  // ---- stage input patch
  if constexpr (INMODE == 0) {
    const unsigned* pin = (const unsigned*)in;
    for (int t = threadIdx.x; t < NCELL; t += NTHR) {
      int col = t % NCOL;
      int row = t / NCOL;
      int gy = y0 - 1 + row, gx = x0 - 1 + col;
      half4 v;
      v[0] = (_Float16)0.f; v[1] = (_Float16)0.f;
      v[2] = (_Float16)0.f; v[3] = (_Float16)0.f;
      if (gy >= 0 && gy < HH && gx >= 0 && gx < WW) {
        unsigned pv = pin[((size_t)b * HH + gy) * WW + gx];
        unsigned cnt = pv & 0xFFu;
        unsigned ivq = (pv >> 8) & 0xFFu;
        unsigned znq = (pv >> 16) & 0xFFu;
        unsigned zxq = pv >> 24;
        float c0, c1, c2, c3;
        if (cnt == 0) { c0 = 0.02f; c1 = 10.f; c2 = -10.f; c3 = 0.f; }
        else {
          c0 = (float)cnt * 0.02f;
          c1 = (float)(255u - znq) * (4.0f / 255.0f) - 3.0f;
          c2 = (float)zxq * (4.0f / 255.0f) - 3.0f;
          c3 = (float)ivq * (1.0f / 255.0f);
        }
        v[0] = (_Float16)c0; v[1] = (_Float16)c1;
        v[2] = (_Float16)c2; v[3] = (_Float16)c3;
      }
      // slot (col>>1): low half = even cell, high half = odd cell
      *(half4*)&s_in[((size_t)row * NSLOT + (col >> 1)) * 8 + (col & 1) * 4] = v;
    }
  } else {
    const _Float16* fin = (const _Float16*)in;       // [b][y][x][CI]
    for (int t = threadIdx.x; t < NCELL; t += NTHR) {
      int col = t % NCOL;
      int row = t / NCOL;
      int gy = y0 - 1 + row, gx = x0 - 1 + col;
      bool okc = (gy >= 0 && gy < HWI && gx >= 0 && gx < HWI);
      int swz = (CIp == 8) ? 0 : ((CIp == 16) ? ((col >> 2) & 1) : ((col >> 1) & 3));
      #pragma unroll
      for (int c8 = 0; c8 < CIp / 8; ++c8) {
        half8 v = zv;
        if (okc)
          v = *(const half8*)((const _Float16*)fin +
                (((size_t)b * HWI + gy) * HWI + gx) * CI + c8 * 8);
        *(half8*)&s_in[(size_t)t * CIp + ((c8 ^ swz) << 3)] = v;
      }
    }
  }
  // ---- stage weights
  if constexpr (INMODE == 0) {
    // cols 0-7: co=col, normal tap-pair table. cols 8-15: co=col-8, x-shifted
    // taps (cell dx 1,2,3 -> w dx 0,1,2); even-p low halves zero.
    for (int t = threadIdx.x; t < COp * KS * 32; t += NTHR) {
      int k   = t % (KS * 32);
      int col = t / (KS * 32);
      int p = k >> 3, j = k & 7;
      int ci = j & 3;
      float v = 0.f;
      if (p < 6) {
        int dy = p >> 1;
        if (col < 8) {
          int tA = p + ((p + 1) >> 1);
          if (j < 4) v = wgt[((size_t)col * CI + ci) * 9 + tA];
          else if ((p & 1) == 0) v = wgt[((size_t)col * CI + ci) * 9 + tA + 1];
        } else {
          int co = col - 8;
          if ((p & 1) == 0) {
            if (j >= 4) v = wgt[((size_t)co * CI + ci) * 9 + dy * 3 + 0];
          } else {
            v = wgt[((size_t)co * CI + ci) * 9 + dy * 3 + ((j < 4) ? 1 : 2)];
          }
        }
      }
      s_w[col * WROW + k] = (_Float16)v;
    }
  } else {
    for (int t = threadIdx.x; t < COp * KS * 32; t += NTHR) {
      int k   = t % (KS * 32);
      int col = t / (KS * 32);
      int cog = cobase + col;
      float v = 0.f;
      if (k < KTOT && cog < COT) {
        int tap = k / CIp, ci = k % CIp;
        if (ci < CI) v = wgt[((size_t)cog * CI + ci) * 9 + tap];
      }
      s_w[col * WROW + k] = (_Float16)v;
    }
  }
  if (threadIdx.x < COp) {
    int col = threadIdx.x;
    int cog = (INMODE == 0) ? (col & 7) : (cobase + col);
    float sc = 0.f, sh = 0.f;
    if (cog < COT) {
      sc = gam[cog] / sqrtf(var[cog] + 1e-5f);
      sh = (bias[cog] - mean[cog]) * sc + bet[cog];
    }
    s_scale[col] = sc; s_shift[col] = sh;
  }
  __syncthreads();

  const int lane = threadIdx.x & 63;
  const int w    = threadIdx.x >> 6;   // wave 0..7, owns y-rows w*4..w*4+3
  const int m    = lane & 15;
  const int hi   = lane >> 4;

  f32x4 acc[4][XH][NT];
  #pragma unroll
  for (int r = 0; r < 4; ++r)
    #pragma unroll
    for (int h = 0; h < XH; ++h)
      #pragma unroll
      for (int n = 0; n < NT; ++n) acc[r][h][n] = 0.f;

  const int y0w = w * 4;
  #pragma unroll
  for (int ks = 0; ks < KS; ++ks) {
    int aoff;
    if constexpr (INMODE == 0) {
      int p = ks * 4 + hi;
      if (p > 5) p = 5;                   // pad groups: finite data x 0 weight
      int dy = p >> 1;
      aoff = ((y0w + dy) * NSLOT + m + (p & 1)) * 8;
    } else {
      int kc  = ks * 32 + (hi << 3);
      int tap = kc >> L2C;
      if (tap > 8) tap = 8;               // pad region: real data * zero weight
      int ci  = kc & (CIp - 1);
      int dy  = (tap * 11) >> 5;          // tap/3 for tap in [0,8]
      int dx  = tap - 3 * dy;
      int colA  = m + dx;
      int chunk = ci >> 3;
      int swz = (CIp == 8) ? 0 : ((CIp == 16) ? ((colA >> 2) & 1) : ((colA >> 1) & 3));
      aoff = ((y0w + dy) * NSLOT + colA) * CIp + ((chunk ^ swz) << 3);
    }
    const int boff = m * WROW + ks * 32 + (hi << 3);
    half8 bfr[NT];
    #pragma unroll
    for (int n = 0; n < NT; ++n)
      bfr[n] = *(const half8*)&s_w[boff + n * 16 * WROW];
    #pragma unroll
    for (int r = 0; r < 4; ++r) {
      half8 afr[XH];
      #pragma unroll
      for (int h = 0; h < XH; ++h)
        afr[h] = *(const half8*)&s_in[aoff + r * NSLOT * CIp + h * 16 * CIp];
      __builtin_amdgcn_s_setprio(1);
      #pragma unroll
      for (int h = 0; h < XH; ++h)
        #pragma unroll
        for (int n = 0; n < NT; ++n)
          acc[r][h][n] = __builtin_amdgcn_mfma_f32_16x16x32_f16(
              afr[h], bfr[n], acc[r][h][n], 0, 0, 0);
      __builtin_amdgcn_s_setprio(0);
    }
  }

  __syncthreads();                       // all LDS reads done; overlay s_in

  if constexpr (POOL && INMODE == 0) {
    // C col n<8: out(x_even, co=n); col n>=8: out(x_even+1, co=n-8).
    // y-pool in-lane (r pairs), x-pool across lanes n<->n+8 (shfl_xor 8).
    _Float16* s_o = (_Float16*)s_raw;    // [yp][xp][COp] f16
    float sc = s_scale[m & 7], sh = s_shift[m & 7];
    #pragma unroll
    for (int rp = 0; rp < 2; ++rp) {
      #pragma unroll
      for (int h = 0; h < XH; ++h) {
        f32x4 p0 = acc[rp * 2][h][0];
        f32x4 p1 = acc[rp * 2 + 1][h][0];
        #pragma unroll
        for (int q = 0; q < 4; ++q) {
          float ym = fmaxf(p0[q], p1[q]);
          float part = __shfl_xor(ym, 8);
          if (m < 8) {
            float v = fmaxf(fmaxf(ym, part) * sc + sh, 0.f);
            int yp = w * 2 + rp;
            int xp = h * 16 + hi * 4 + q;
            s_o[(yp * PXH + xp) * COp + m] = (_Float16)v;
          }
        }
      }
    }
    __syncthreads();
    constexpr int HWO = HWI / 2;
    _Float16* og = (_Float16*)outv;      // [b][HWO][HWO][COT=8]
    for (int t = threadIdx.x; t < 16 * PXH; t += NTHR) {
      int xp = t % PXH;
      int yp = t / PXH;
      half8 v = *(const half8*)&s_o[(yp * PXH + xp) * COp];
      *(half8*)&og[(((size_t)b * HWO + (y0 / 2 + yp)) * HWO + (x0 / 2 + xp)) * COT] = v;
    }
  } else if constexpr (POOL) {
    // lane holds conv x = hi*4+q at y-row r; pool x-pairs in-lane, y-pairs
    // across r. Pooled yp = w*2+rp (0..15), xp = h*8+hi*2+{0,1}.
    _Float16* s_o = (_Float16*)s_raw;    // [yp][xp][COp] f16
    #pragma unroll
    for (int n = 0; n < NT; ++n) {
      int col = n * 16 + m;
      float sc = s_scale[col], sh = s_shift[col];
      #pragma unroll
      for (int rp = 0; rp < 2; ++rp) {
        #pragma unroll
        for (int h = 0; h < XH; ++h) {
          f32x4 p0 = acc[rp * 2][h][n];
          f32x4 p1 = acc[rp * 2 + 1][h][n];
          float v0 = fmaxf(fmaxf(p0[0], p0[1]), fmaxf(p1[0], p1[1]));
          float v1 = fmaxf(fmaxf(p0[2], p0[3]), fmaxf(p1[2], p1[3]));
          v0 = fmaxf(v0 * sc + sh, 0.f);
          v1 = fmaxf(v1 * sc + sh, 0.f);
          int yp = w * 2 + rp;
          int xp = h * 8 + hi * 2;
          s_o[(yp * PXH + xp) * COp + col]     = (_Float16)v0;
          s_o[(yp * PXH + xp + 1) * COp + col] = (_Float16)v1;
        }
      }
    }
    __syncthreads();
    constexpr int HWO = HWI / 2;
    constexpr int NCHG = (COR + 7) / 8;  // 8-chunks this group writes
    _Float16* og = (_Float16*)outv;      // [b][HWO][HWO][COT]
    for (int t = threadIdx.x; t < 16 * PXH * NCHG; t += NTHR) {
      int c8  = t % NCHG;
      int rem = t / NCHG;
      int xp  = rem % PXH;
      int yp  = rem / PXH;
      half8 v = *(const half8*)&s_o[(yp * PXH + xp) * COp + c8 * 8];
      *(half8*)&og[(((size_t)b * HWO + (y0 / 2 + yp)) * HWO + (x0 / 2 + xp)) * COT
                   + cobase + c8 * 8] = v;
    }
  } else {
    // final layer: NCHW f32 out; 4 rounds staging one y-row per wave
    float* s_out = (float*)s_raw;
    float* og = (float*)outv;
    #pragma unroll
    for (int r = 0; r < 4; ++r) {
      if (r) __syncthreads();
      #pragma unroll
      for (int n = 0; n < NT; ++n) {
        int col = n * 16 + m;
        float sc = s_scale[col], sh = s_shift[col];
        f32x4 p = acc[r][0][n];
        #pragma unroll
        for (int q = 0; q < 4; ++q) {
          float v = fmaxf(p[q] * sc + sh, 0.f);
          s_out[col * OCS + w * 16 + hi * 4 + q] = v;
        }
      }
      __syncthreads();
      for (int t = threadIdx.x; t < COR * 8 * 16; t += NTHR) {
        int xp = t & 15, ws3 = (t >> 4) & 7, col = t >> 7;
        og[(((size_t)b * COT + cobase + col) * HWI + (y0 + ws3 * 4 + r)) * HWI + (x0 + xp)]
          = s_out[col * OCS + ws3 * 16 + xp];
      }
    }
  }
}

extern "C" void kernel_launch(void* const* d_in, const int* in_sizes, int n_in,
                              void* d_out, int out_size, void* d_ws, size_t ws_size,
                              hipStream_t stream) {
  const float* pts = (const float*)d_in[0];
  const int npts = in_sizes[0] / 5;

  const float* w1  = (const float*)d_in[2];
  const float* b1  = (const float*)d_in[3];
  const float* g1  = (const float*)d_in[4];
  const float* be1 = (const float*)d_in[5];
  const float* m1  = (const float*)d_in[6];
  const float* v1  = (const float*)d_in[7];
  const float* w2  = (const float*)d_in[8];
  const float* b2  = (const float*)d_in[9];
  const float* g2  = (const float*)d_in[10];
  const float* be2 = (const float*)d_in[11];
  const float* m2  = (const float*)d_in[12];
  const float* v2  = (const float*)d_in[13];
  const float* w3  = (const float*)d_in[14];
  const float* b3  = (const float*)d_in[15];
  const float* g3  = (const float*)d_in[16];
  const float* be3 = (const float*)d_in[17];
  const float* m3  = (const float*)d_in[18];
  const float* v3  = (const float*)d_in[19];
  const float* w4  = (const float*)d_in[20];
  const float* b4  = (const float*)d_in[21];
  const float* g4  = (const float*)d_in[22];
  const float* be4 = (const float*)d_in[23];
  const float* m4  = (const float*)d_in[24];
  const float* v4  = (const float*)d_in[25];

  char* ws = (char*)d_ws;
  // Workspace (bytes):
  //   packed cells [0, 16M): u32 per cell
  //   l1 [32M, 48M):  f16 CL (4,512,512,8)
  //   l2 [48M, 56.4M): f16 CL (4,256,256,16)
  //   l3 [56.4M, 60.6M): f16 CL (4,128,128,32)
  unsigned* packed = (unsigned*)ws;
  void* l1 = (void*)(ws + 33554432);
  void* l2 = (void*)(ws + 50331648);
  void* l3 = (void*)(ws + 58720256);
  void* outp = d_out;

  clear_cells<<<2048, 256, 0, stream>>>((float4*)packed, (int)((size_t)NB * HH * WW * 4 / 16));
  scatter_points_packed<<<(npts + 255) / 256, 256, 0, stream>>>(pts, npts, packed);

  // <CI, CIp, COT, COp, HWI, PXT, KS, POOL, INMODE, OUTCL>, 512-thread blocks
  conv_mfma<4,  8,  8,  16, 1024, 64, 2, true,  0, true ><<<dim3(512, 1, 4), 512, 0, stream>>>(packed, l1, w1, b1, g1, be1, m1, v1);
  conv_mfma<8,  8,  16, 16, 512,  64, 3, true,  1, true ><<<dim3(128, 1, 4), 512, 0, stream>>>(l1,  l2, w2, b2, g2, be2, m2, v2);
  conv_mfma<16, 16, 32, 16, 256,  32, 5, true,  1, true ><<<dim3(64,  2, 4), 512, 0, stream>>>(l2,  l3, w3, b3, g3, be3, m3, v3);
  conv_mfma<32, 32, 64, 16, 128,  16, 9, false, 1, false><<<dim3(32,  4, 4), 512, 0, stream>>>(l3, outp, w4, b4, g4, be4, m4, v4);
}

// Round 14
// 92.084 us; speedup vs baseline: 1.6379x; 1.0194x over previous
//
#include <hip/hip_runtime.h>
#include <cstdint>
#include <cstddef>

#define HH 1024
#define WW 1024
#define NB 4

typedef _Float16 half8 __attribute__((ext_vector_type(8)));
typedef _Float16 half4 __attribute__((ext_vector_type(4)));
typedef float f32x4 __attribute__((ext_vector_type(4)));
typedef unsigned long long ull;

// Direct global->LDS (16B/lane, wave-uniform LDS base + lane*16).
__device__ __forceinline__ void glds16(const void* g, void* l) {
  __builtin_amdgcn_global_load_lds(
      (const __attribute__((address_space(1))) void*)g,
      (__attribute__((address_space(3))) void*)l, 16, 0, 0);
}

// ---------------------------------------------------------------------------
// Fast clear for the 16 MB packed-cell buffer + 64B zero-scratch (~5.5 TB/s).
// ---------------------------------------------------------------------------
__global__ __launch_bounds__(256)
void clear_cells(float4* __restrict__ p, int n4) {
  int stride = gridDim.x * blockDim.x;
  float4 z; z.x = 0.f; z.y = 0.f; z.z = 0.f; z.w = 0.f;
  for (int i = blockIdx.x * blockDim.x + threadIdx.x; i < n4; i += stride)
    p[i] = z;
}

// ---------------------------------------------------------------------------
// Scatter: 4 per-cell stats packed in ONE u32 updated by CAS.
//   [31:24] zmax_q8 | [23:16] 255-zmin_q8 | [15:8] iv_q8 | [7:0] cnt (sat 255)
// All-zero word == empty cell. Optimistic first CAS (~90% one-shot).
// R10 lesson: scatter is atomic-OP-RATE bound (~24 G CAS/s), not line-bound.
// ---------------------------------------------------------------------------
__device__ __forceinline__ unsigned merge_cell(unsigned a, unsigned zq,
                                               unsigned zn, unsigned iq) {
  unsigned cnt = a & 0xFFu;
  unsigned civ = (a >> 8) & 0xFFu;
  unsigned czn = (a >> 16) & 0xFFu;
  unsigned czx = a >> 24;
  cnt = (cnt < 255u) ? cnt + 1u : cnt;
  civ = civ > iq ? civ : iq;
  czn = czn > zn ? czn : zn;
  czx = czx > zq ? czx : zq;
  return cnt | (civ << 8) | (czn << 16) | (czx << 24);
}

__global__ __launch_bounds__(256)
void scatter_points_packed(const float* __restrict__ pts, int n,
                           unsigned* __restrict__ cell) {
  const float xs   = (float)(1024.0 / 69.12);
  const float ys   = (float)(1024.0 / (39.68 + 39.68));
  const float yoff = 39.68f;
  int i = blockIdx.x * blockDim.x + threadIdx.x;
  if (i >= n) return;
  float b  = pts[(size_t)i * 5 + 0];
  float x  = pts[(size_t)i * 5 + 1];
  float y  = pts[(size_t)i * 5 + 2];
  float z  = pts[(size_t)i * 5 + 3];
  float it = pts[(size_t)i * 5 + 4];
  int xp = (int)(x * xs);                 // trunc toward zero == astype(int32)
  int yp = (int)((y + yoff) * ys);
  if (xp < 0 || xp >= WW || yp < 0 || yp >= HH) return;
  int lin = ((int)b * HH + yp) * WW + xp;

  float zc = fminf(fmaxf(z, -3.f), 1.f);
  unsigned zq = (unsigned)(int)((zc + 3.f) * (255.f / 4.f) + 0.5f);
  if (zq > 255u) zq = 255u;
  float ic = fminf(fmaxf(it, 0.f), 1.f);
  unsigned iq = (unsigned)(int)(ic * 255.f + 0.5f);
  if (iq > 255u) iq = 255u;
  unsigned zn = 255u - zq;

  unsigned g = atomicCAS(&cell[lin], 0u, merge_cell(0u, zq, zn, iq));
  while (g != 0u) {
    unsigned r = atomicCAS(&cell[lin], g, merge_cell(g, zq, zn, iq));
    if (r == g) break;
    g = r;
  }
}

// ---------------------------------------------------------------------------
// Implicit-GEMM conv3x3 + bias + BN + ReLU (+2x2 maxpool) via MFMA f16.
// 512 threads / 8 waves per block; 32 y-rows x PXT x-cols, co group
// [cobase, cobase+COp). Wave w owns y-rows w*4..w*4+3.
// INMODE 0 (conv1, packed-u32 BEV, CI=4, CO=8): dual-x N-packing (see R13).
// INMODE 1: channels-last f16 [b][y][x][CI]; staging via global_load_lds
//   (direct-to-LDS, 16B/lane): lane ck slot loads global chunk (ck^swz) so
//   the read-side XOR is unchanged (pre-swizzled-source pattern). Halo/tail
//   lanes source a zeroed 64B scratch (gzero). LDS padded to whole issues.
// OUTCL: true = channels-last f16 out; false = NCHW f32 (final layer).
// NOTE: LDS A-fragment loads must stay 16B-aligned (slot stride multiple of
// 8 f16) or ds_read_b128 scalarizes — R8's CIp=4 packing cost 3x (72us).
// ---------------------------------------------------------------------------
template<int CI, int CIp, int COT, int COp, int HWI, int PXT, int KS,
         bool POOL, int INMODE, bool OUTCL>
__global__ __launch_bounds__(512)
void conv_mfma(const void* __restrict__ in, void* __restrict__ outv,
               const float* __restrict__ wgt, const float* __restrict__ bias,
               const float* __restrict__ gam, const float* __restrict__ bet,
               const float* __restrict__ mean, const float* __restrict__ var,
               const void* __restrict__ gzero) {
  constexpr int PYT  = 32;
  constexpr int NTHR = 512;
  constexpr int NT   = COp / 16;
  constexpr int XH   = (INMODE == 0) ? (PXT / 32) : (PXT / 16);
  constexpr int NCOL = PXT + 2;
  constexpr int NSLOT = (INMODE == 0) ? ((NCOL + 1) / 2) : NCOL;
  constexpr int NCELL = (PYT + 2) * NCOL;
  constexpr int WROW = KS * 32 + 8;
  constexpr int INE  = (PYT + 2) * NSLOT * CIp;
  // glds staging geometry (INMODE 1)
  constexpr int CH   = CIp / 8;                 // 16B chunks per cell
  constexpr int LOG2CH = (CH == 1) ? 0 : ((CH == 2) ? 1 : 2);
  constexpr int CPW  = 64 / CH;                 // cells per wave per issue
  constexpr int CPI  = NTHR / CH;               // cells per block-iteration
  constexpr int NCELLP = ((NCELL + CPI - 1) / CPI) * CPI;
  constexpr int INEPAD = (INMODE == 1) ? (NCELLP * CIp) : INE;
  constexpr int L2C  = (CIp == 8) ? 3 : ((CIp == 16) ? 4 : 5);
  constexpr int KTOT = 9 * CIp;
  constexpr int COR  = (COT < COp) ? COT : COp;
  constexpr int PXH  = PXT / 2;
  constexpr int OCS  = 136;              // no-pool out-stage stride (floats)
  static_assert(CIp % 8 == 0 && COp % 16 == 0, "");
  static_assert(INMODE != 0 || (CI == 4 && CIp == 8 && KS == 2 && COT == 8 && COp == 16), "");
  static_assert(INMODE != 1 || CI == CIp, "glds staging assumes CI==CIp");
  static_assert(!OUTCL || (POOL && COT % 8 == 0), "");
  static_assert(!POOL || 16 * PXH * COp * 2 <= INEPAD * 2, "out overlay fits");
  static_assert(POOL || COp * OCS * 4 <= INEPAD * 2, "out overlay fits");

  __shared__ __align__(16) char s_raw[INEPAD * 2 + COp * WROW * 2 + COp * 8];
  _Float16* s_in = (_Float16*)s_raw;
  _Float16* s_w  = (_Float16*)(s_raw + INEPAD * 2);
  float* s_scale = (float*)(s_raw + INEPAD * 2 + (size_t)COp * WROW * 2);
  float* s_shift = s_scale + COp;

  const int cobase = blockIdx.y * COp;
  const int b = blockIdx.z;
  constexpr int NPX = HWI / PXT;
  const int pyi = blockIdx.x / NPX;
  const int pxi = blockIdx.x - pyi * NPX;
  const int y0 = pyi * PYT, x0 = pxi * PXT;

  half8 zv;
  #pragma unroll
  for (int q = 0; q < 8; ++q) zv[q] = (_Float16)0.f;

  // ---- stage input patch
  if constexpr (INMODE == 0) {
    const unsigned* pin = (const unsigned*)in;
    for (int t = threadIdx.x; t < NCELL; t += NTHR) {
      int col = t % NCOL;
      int row = t / NCOL;
      int gy = y0 - 1 + row, gx = x0 - 1 + col;
      half4 v;
      v[0] = (_Float16)0.f; v[1] = (_Float16)0.f;
      v[2] = (_Float16)0.f; v[3] = (_Float16)0.f;
      if (gy >= 0 && gy < HH && gx >= 0 && gx < WW) {
        unsigned pv = pin[((size_t)b * HH + gy) * WW + gx];
        unsigned cnt = pv & 0xFFu;
        unsigned ivq = (pv >> 8) & 0xFFu;
        unsigned znq = (pv >> 16) & 0xFFu;
        unsigned zxq = pv >> 24;
        float c0, c1, c2, c3;
        if (cnt == 0) { c0 = 0.02f; c1 = 10.f; c2 = -10.f; c3 = 0.f; }
        else {
          c0 = (float)cnt * 0.02f;
          c1 = (float)(255u - znq) * (4.0f / 255.0f) - 3.0f;
          c2 = (float)zxq * (4.0f / 255.0f) - 3.0f;
          c3 = (float)ivq * (1.0f / 255.0f);
        }
        v[0] = (_Float16)c0; v[1] = (_Float16)c1;
        v[2] = (_Float16)c2; v[3] = (_Float16)c3;
      }
      // slot (col>>1): low half = even cell, high half = odd cell
      *(half4*)&s_in[((size_t)row * NSLOT + (col >> 1)) * 8 + (col & 1) * 4] = v;
    }
  } else {
    const _Float16* fin = (const _Float16*)in;       // [b][y][x][CI]
    const int wv = threadIdx.x >> 6;
    const int ln = threadIdx.x & 63;
    const int ck = ln & (CH - 1);
    const int ciw = ln >> LOG2CH;                    // cell-in-wave
    #pragma unroll 1
    for (int base = 0; base < NCELLP; base += CPI) {
      int t = base + wv * CPW + ciw;
      int col = t % NCOL;
      int row = t / NCOL;
      int gy = y0 - 1 + row, gx = x0 - 1 + col;
      bool okc = (t < NCELL) && (gy >= 0) && (gy < HWI) && (gx >= 0) && (gx < HWI);
      int swz = (CIp == 8) ? 0 : ((CIp == 16) ? ((col >> 2) & 1) : ((col >> 1) & 3));
      const void* src = okc
        ? (const void*)(fin + (((size_t)b * HWI + gy) * HWI + gx) * CI + ((ck ^ swz) << 3))
        : gzero;
      void* dst = (void*)((char*)s_raw + (size_t)(base + wv * CPW) * CIp * 2);
      glds16(src, dst);
    }
  }
  // ---- stage weights
  if constexpr (INMODE == 0) {
    // cols 0-7: co=col, normal tap-pair table. cols 8-15: co=col-8, x-shifted
    // taps (cell dx 1,2,3 -> w dx 0,1,2); even-p low halves zero.
    for (int t = threadIdx.x; t < COp * KS * 32; t += NTHR) {
      int k   = t % (KS * 32);
      int col = t / (KS * 32);
      int p = k >> 3, j = k & 7;
      int ci = j & 3;
      float v = 0.f;
      if (p < 6) {
        int dy = p >> 1;
        if (col < 8) {
          int tA = p + ((p + 1) >> 1);
          if (j < 4) v = wgt[((size_t)col * CI + ci) * 9 + tA];
          else if ((p & 1) == 0) v = wgt[((size_t)col * CI + ci) * 9 + tA + 1];
        } else {
          int co = col - 8;
          if ((p & 1) == 0) {
            if (j >= 4) v = wgt[((size_t)co * CI + ci) * 9 + dy * 3 + 0];
          } else {
            v = wgt[((size_t)co * CI + ci) * 9 + dy * 3 + ((j < 4) ? 1 : 2)];
          }
        }
      }
      s_w[col * WROW + k] = (_Float16)v;
    }
  } else {
    for (int t = threadIdx.x; t < COp * KS * 32; t += NTHR) {
      int k   = t % (KS * 32);
      int col = t / (KS * 32);
      int cog = cobase + col;
      float v = 0.f;
      if (k < KTOT && cog < COT) {
        int tap = k / CIp, ci = k % CIp;
        if (ci < CI) v = wgt[((size_t)cog * CI + ci) * 9 + tap];
      }
      s_w[col * WROW + k] = (_Float16)v;
    }
  }
  if (threadIdx.x < COp) {
    int col = threadIdx.x;
    int cog = (INMODE == 0) ? (col & 7) : (cobase + col);
    float sc = 0.f, sh = 0.f;
    if (cog < COT) {
      sc = gam[cog] / sqrtf(var[cog] + 1e-5f);
      sh = (bias[cog] - mean[cog]) * sc + bet[cog];
    }
    s_scale[col] = sc; s_shift[col] = sh;
  }
  __syncthreads();   // drains vmcnt(0): all glds transfers complete

  const int lane = threadIdx.x & 63;
  const int w    = threadIdx.x >> 6;   // wave 0..7, owns y-rows w*4..w*4+3
  const int m    = lane & 15;
  const int hi   = lane >> 4;

  f32x4 acc[4][XH][NT];
  #pragma unroll
  for (int r = 0; r < 4; ++r)
    #pragma unroll
    for (int h = 0; h < XH; ++h)
      #pragma unroll
      for (int n = 0; n < NT; ++n) acc[r][h][n] = 0.f;

  const int y0w = w * 4;
  #pragma unroll
  for (int ks = 0; ks < KS; ++ks) {
    int aoff;
    if constexpr (INMODE == 0) {
      int p = ks * 4 + hi;
      if (p > 5) p = 5;                   // pad groups: finite data x 0 weight
      int dy = p >> 1;
      aoff = ((y0w + dy) * NSLOT + m + (p & 1)) * 8;
    } else {
      int kc  = ks * 32 + (hi << 3);
      int tap = kc >> L2C;
      if (tap > 8) tap = 8;               // pad region: real data * zero weight
      int ci  = kc & (CIp - 1);
      int dy  = (tap * 11) >> 5;          // tap/3 for tap in [0,8]
      int dx  = tap - 3 * dy;
      int colA  = m + dx;
      int chunk = ci >> 3;
      int swz = (CIp == 8) ? 0 : ((CIp == 16) ? ((colA >> 2) & 1) : ((colA >> 1) & 3));
      aoff = ((y0w + dy) * NSLOT + colA) * CIp + ((chunk ^ swz) << 3);
    }
    const int boff = m * WROW + ks * 32 + (hi << 3);
    half8 bfr[NT];
    #pragma unroll
    for (int n = 0; n < NT; ++n)
      bfr[n] = *(const half8*)&s_w[boff + n * 16 * WROW];
    #pragma unroll
    for (int r = 0; r < 4; ++r) {
      half8 afr[XH];
      #pragma unroll
      for (int h = 0; h < XH; ++h)
        afr[h] = *(const half8*)&s_in[aoff + r * NSLOT * CIp + h * 16 * CIp];
      __builtin_amdgcn_s_setprio(1);
      #pragma unroll
      for (int h = 0; h < XH; ++h)
        #pragma unroll
        for (int n = 0; n < NT; ++n)
          acc[r][h][n] = __builtin_amdgcn_mfma_f32_16x16x32_f16(
              afr[h], bfr[n], acc[r][h][n], 0, 0, 0);
      __builtin_amdgcn_s_setprio(0);
    }
  }

  __syncthreads();                       // all LDS reads done; overlay s_in

  if constexpr (POOL && INMODE == 0) {
    // C col n<8: out(x_even, co=n); col n>=8: out(x_even+1, co=n-8).
    // y-pool in-lane (r pairs), x-pool across lanes n<->n+8 (shfl_xor 8).
    _Float16* s_o = (_Float16*)s_raw;    // [yp][xp][COp] f16
    float sc = s_scale[m & 7], sh = s_shift[m & 7];
    #pragma unroll
    for (int rp = 0; rp < 2; ++rp) {
      #pragma unroll
      for (int h = 0; h < XH; ++h) {
        f32x4 p0 = acc[rp * 2][h][0];
        f32x4 p1 = acc[rp * 2 + 1][h][0];
        #pragma unroll
        for (int q = 0; q < 4; ++q) {
          float ym = fmaxf(p0[q], p1[q]);
          float part = __shfl_xor(ym, 8);
          if (m < 8) {
            float v = fmaxf(fmaxf(ym, part) * sc + sh, 0.f);
            int yp = w * 2 + rp;
            int xp = h * 16 + hi * 4 + q;
            s_o[(yp * PXH + xp) * COp + m] = (_Float16)v;
          }
        }
      }
    }
    __syncthreads();
    constexpr int HWO = HWI / 2;
    _Float16* og = (_Float16*)outv;      // [b][HWO][HWO][COT=8]
    for (int t = threadIdx.x; t < 16 * PXH; t += NTHR) {
      int xp = t % PXH;
      int yp = t / PXH;
      half8 v = *(const half8*)&s_o[(yp * PXH + xp) * COp];
      *(half8*)&og[(((size_t)b * HWO + (y0 / 2 + yp)) * HWO + (x0 / 2 + xp)) * COT] = v;
    }
  } else if constexpr (POOL) {
    // lane holds conv x = hi*4+q at y-row r; pool x-pairs in-lane, y-pairs
    // across r. Pooled yp = w*2+rp (0..15), xp = h*8+hi*2+{0,1}.
    _Float16* s_o = (_Float16*)s_raw;    // [yp][xp][COp] f16
    #pragma unroll
    for (int n = 0; n < NT; ++n) {
      int col = n * 16 + m;
      float sc = s_scale[col], sh = s_shift[col];
      #pragma unroll
      for (int rp = 0; rp < 2; ++rp) {
        #pragma unroll
        for (int h = 0; h < XH; ++h) {
          f32x4 p0 = acc[rp * 2][h][n];
          f32x4 p1 = acc[rp * 2 + 1][h][n];
          float v0 = fmaxf(fmaxf(p0[0], p0[1]), fmaxf(p1[0], p1[1]));
          float v1 = fmaxf(fmaxf(p0[2], p0[3]), fmaxf(p1[2], p1[3]));
          v0 = fmaxf(v0 * sc + sh, 0.f);
          v1 = fmaxf(v1 * sc + sh, 0.f);
          int yp = w * 2 + rp;
          int xp = h * 8 + hi * 2;
          s_o[(yp * PXH + xp) * COp + col]     = (_Float16)v0;
          s_o[(yp * PXH + xp + 1) * COp + col] = (_Float16)v1;
        }
      }
    }
    __syncthreads();
    constexpr int HWO = HWI / 2;
    constexpr int NCHG = (COR + 7) / 8;  // 8-chunks this group writes
    _Float16* og = (_Float16*)outv;      // [b][HWO][HWO][COT]
    for (int t = threadIdx.x; t < 16 * PXH * NCHG; t += NTHR) {
      int c8  = t % NCHG;
      int rem = t / NCHG;
      int xp  = rem % PXH;
      int yp  = rem / PXH;
      half8 v = *(const half8*)&s_o[(yp * PXH + xp) * COp + c8 * 8];
      *(half8*)&og[(((size_t)b * HWO + (y0 / 2 + yp)) * HWO + (x0 / 2 + xp)) * COT
                   + cobase + c8 * 8] = v;
    }
  } else {
    // final layer: NCHW f32 out; 4 rounds staging one y-row per wave
    float* s_out = (float*)s_raw;
    float* og = (float*)outv;
    #pragma unroll
    for (int r = 0; r < 4; ++r) {
      if (r) __syncthreads();
      #pragma unroll
      for (int n = 0; n < NT; ++n) {
        int col = n * 16 + m;
        float sc = s_scale[col], sh = s_shift[col];
        f32x4 p = acc[r][0][n];
        #pragma unroll
        for (int q = 0; q < 4; ++q) {
          float v = fmaxf(p[q] * sc + sh, 0.f);
          s_out[col * OCS + w * 16 + hi * 4 + q] = v;
        }
      }
      __syncthreads();
      for (int t = threadIdx.x; t < COR * 8 * 16; t += NTHR) {
        int xp = t & 15, ws3 = (t >> 4) & 7, col = t >> 7;
        og[(((size_t)b * COT + cobase + col) * HWI + (y0 + ws3 * 4 + r)) * HWI + (x0 + xp)]
          = s_out[col * OCS + ws3 * 16 + xp];
      }
    }
  }
}

extern "C" void kernel_launch(void* const* d_in, const int* in_sizes, int n_in,
                              void* d_out, int out_size, void* d_ws, size_t ws_size,
                              hipStream_t stream) {
  const float* pts = (const float*)d_in[0];
  const int npts = in_sizes[0] / 5;

  const float* w1  = (const float*)d_in[2];
  const float* b1  = (const float*)d_in[3];
  const float* g1  = (const float*)d_in[4];
  const float* be1 = (const float*)d_in[5];
  const float* m1  = (const float*)d_in[6];
  const float* v1  = (const float*)d_in[7];
  const float* w2  = (const float*)d_in[8];
  const float* b2  = (const float*)d_in[9];
  const float* g2  = (const float*)d_in[10];
  const float* be2 = (const float*)d_in[11];
  const float* m2  = (const float*)d_in[12];
  const float* v2  = (const float*)d_in[13];
  const float* w3  = (const float*)d_in[14];
  const float* b3  = (const float*)d_in[15];
  const float* g3  = (const float*)d_in[16];
  const float* be3 = (const float*)d_in[17];
  const float* m3  = (const float*)d_in[18];
  const float* v3  = (const float*)d_in[19];
  const float* w4  = (const float*)d_in[20];
  const float* b4  = (const float*)d_in[21];
  const float* g4  = (const float*)d_in[22];
  const float* be4 = (const float*)d_in[23];
  const float* m4  = (const float*)d_in[24];
  const float* v4  = (const float*)d_in[25];

  char* ws = (char*)d_ws;
  // Workspace (bytes):
  //   packed cells [0, 16M): u32 per cell
  //   gzero [16M, 16M+64): zeroed scratch for glds halo lanes
  //   l1 [32M, 48M):  f16 CL (4,512,512,8)
  //   l2 [48M, 56.4M): f16 CL (4,256,256,16)
  //   l3 [56.4M, 60.6M): f16 CL (4,128,128,32)
  unsigned* packed = (unsigned*)ws;
  const void* gz = (const void*)(ws + 16777216);
  void* l1 = (void*)(ws + 33554432);
  void* l2 = (void*)(ws + 50331648);
  void* l3 = (void*)(ws + 58720256);
  void* outp = d_out;

  // 16 MB cells + 64B gzero = 1048580 float4s
  clear_cells<<<2048, 256, 0, stream>>>((float4*)packed, 1048580);
  scatter_points_packed<<<(npts + 255) / 256, 256, 0, stream>>>(pts, npts, packed);

  // <CI, CIp, COT, COp, HWI, PXT, KS, POOL, INMODE, OUTCL>, 512-thread blocks
  conv_mfma<4,  8,  8,  16, 1024, 64, 2, true,  0, true ><<<dim3(512, 1, 4), 512, 0, stream>>>(packed, l1, w1, b1, g1, be1, m1, v1, gz);
  conv_mfma<8,  8,  16, 16, 512,  64, 3, true,  1, true ><<<dim3(128, 1, 4), 512, 0, stream>>>(l1,  l2, w2, b2, g2, be2, m2, v2, gz);
  conv_mfma<16, 16, 32, 16, 256,  32, 5, true,  1, true ><<<dim3(64,  2, 4), 512, 0, stream>>>(l2,  l3, w3, b3, g3, be3, m3, v3, gz);
  conv_mfma<32, 32, 64, 16, 128,  16, 9, false, 1, false><<<dim3(32,  4, 4), 512, 0, stream>>>(l3, outp, w4, b4, g4, be4, m4, v4, gz);
}